// Round 3
// baseline (543.377 us; speedup 1.0000x reference)
//
#include <hip/hip_runtime.h>

using half8 = __attribute__((ext_vector_type(8))) _Float16;
using f32x4 = __attribute__((ext_vector_type(4))) float;

#define MFMA16(a,b,c) __builtin_amdgcn_mfma_f32_16x16x32_f16((a),(b),(c),0,0,0)

constexpr int DM = 1024;
constexpr int NH = 16;
constexpr int HD = 64;
constexpr int LQ = 256, LV = 576, PP = 2048, LC = 256;
constexpr int KVC = LV + LC;            // 832 (vis rows 0..575, cur rows 576..831)
constexpr float SCALE = 0.125f;         // 1/sqrt(64)

// ---------------- W -> W^T fp16 (4 matrices) ----------------
__global__ __launch_bounds__(256) void wtrans_k(
    const float* __restrict__ W0, const float* __restrict__ W1,
    const float* __restrict__ W2, const float* __restrict__ W3,
    _Float16* __restrict__ T0, _Float16* __restrict__ T1,
    _Float16* __restrict__ T2, _Float16* __restrict__ T3)
{
  __shared__ float t[64][65];
  const float* W = blockIdx.z==0 ? W0 : blockIdx.z==1 ? W1 : blockIdx.z==2 ? W2 : W3;
  _Float16*   T  = blockIdx.z==0 ? T0 : blockIdx.z==1 ? T1 : blockIdx.z==2 ? T2 : T3;
  const int k0 = blockIdx.x*64, n0 = blockIdx.y*64;
  const int r = threadIdx.x >> 2, c0 = (threadIdx.x & 3)*16;
  const float* src = W + (size_t)(k0+r)*DM + n0 + c0;
  #pragma unroll
  for (int j=0;j<4;++j) {
    f32x4 v = *(const f32x4*)(src + 4*j);
    #pragma unroll
    for (int i=0;i<4;++i) t[r][c0+4*j+i] = v[i];
  }
  __syncthreads();
  // thread writes Wt row (n0+r), cols k0+c0..+15 : Wt[n][k] = W[k][n] = t[k_local][n_local]
  half8 o0, o1;
  #pragma unroll
  for (int i=0;i<8;++i) { o0[i] = (_Float16)t[c0+i][r]; o1[i] = (_Float16)t[c0+8+i][r]; }
  _Float16* dst = T + (size_t)(n0+r)*DM + k0 + c0;
  *(half8*)dst = o0;
  *(half8*)(dst+8) = o1;
}

// ---------------- generic NT GEMM: C[M,1024] = A[M,1024] @ Wt^T + bias ----------------
// AF16: A is fp16 (else fp32). MODE 0: write fp16 head-split layout
//       dst[((b*NH+h)*LK + off + pos)*64 + d], b=t/L, pos=t%L, col=h*64+d.
// MODE 1: write fp32 flat dst[t*1024+col].
template<bool AF16, int MODE>
__global__ __launch_bounds__(256) void gemm_k(
    const void* __restrict__ Av, const _Float16* __restrict__ Wt,
    const float* __restrict__ bias, void* __restrict__ outv,
    int L, int off, int LK)
{
  __shared__ __align__(16) _Float16 As[128*40];
  __shared__ __align__(16) _Float16 Bs[128*40];
  const int tid = threadIdx.x;
  const int lane = tid & 63, wid = tid >> 6;
  const int l15 = lane & 15, l4 = lane >> 4;
  const int wm = wid >> 1, wn = wid & 1;           // 2x2 waves, 64x64 each
  const int m0 = blockIdx.x*128, n0 = blockIdx.y*128;
  const int sr = tid >> 1, sc = (tid & 1)*16;      // staging: row 0..127, k-offset 0/16

  _Float16 hv[16], wv[16];

  auto loadT = [&](int kt) {
    if constexpr (AF16) {
      const _Float16* ap = (const _Float16*)Av + (size_t)(m0+sr)*DM + kt*32 + sc;
      half8 x = *(const half8*)ap, y = *(const half8*)(ap+8);
      #pragma unroll
      for (int i=0;i<8;++i){ hv[i]=x[i]; hv[8+i]=y[i]; }
    } else {
      const float* ap = (const float*)Av + (size_t)(m0+sr)*DM + kt*32 + sc;
      #pragma unroll
      for (int j=0;j<4;++j){
        f32x4 v = *(const f32x4*)(ap+4*j);
        #pragma unroll
        for (int i=0;i<4;++i) hv[4*j+i] = (_Float16)v[i];
      }
    }
    const _Float16* wp = Wt + (size_t)(n0+sr)*DM + kt*32 + sc;
    half8 x = *(const half8*)wp, y = *(const half8*)(wp+8);
    #pragma unroll
    for (int i=0;i<8;++i){ wv[i]=x[i]; wv[8+i]=y[i]; }
  };

  f32x4 acc[4][4] = {};
  loadT(0);

  for (int kt=0; kt<32; ++kt) {
    __syncthreads();
    {
      half8 a0,a1,b0,b1;
      #pragma unroll
      for (int i=0;i<8;++i){ a0[i]=hv[i]; a1[i]=hv[8+i]; b0[i]=wv[i]; b1[i]=wv[8+i]; }
      *(half8*)&As[sr*40+sc]   = a0;
      *(half8*)&As[sr*40+sc+8] = a1;
      *(half8*)&Bs[sr*40+sc]   = b0;
      *(half8*)&Bs[sr*40+sc+8] = b1;
    }
    __syncthreads();
    if (kt < 31) loadT(kt+1);   // overlap next-tile global loads with compute

    half8 af[4], bf[4];
    #pragma unroll
    for (int mf=0;mf<4;++mf) af[mf] = *(const half8*)&As[(wm*64+mf*16+l15)*40 + l4*8];
    #pragma unroll
    for (int nf=0;nf<4;++nf) bf[nf] = *(const half8*)&Bs[(wn*64+nf*16+l15)*40 + l4*8];
    #pragma unroll
    for (int mf=0;mf<4;++mf)
      #pragma unroll
      for (int nf=0;nf<4;++nf)
        acc[mf][nf] = MFMA16(af[mf], bf[nf], acc[mf][nf]);
  }

  // epilogue
  #pragma unroll
  for (int nf=0;nf<4;++nf) {
    const int col = n0 + wn*64 + nf*16 + l15;
    const float bv = bias[col];
    const int hh = col >> 6, dd = col & 63;
    #pragma unroll
    for (int mf=0;mf<4;++mf) {
      const int rbase = m0 + wm*64 + mf*16 + l4*4;
      #pragma unroll
      for (int r=0;r<4;++r) {
        const int t = rbase + r;
        const float v = acc[mf][nf][r] + bv;
        if constexpr (MODE==0) {
          const int bb = t / L, pos = t - bb*L;
          ((_Float16*)outv)[ ((size_t)((bb*NH + hh)*LK + off + pos))*HD + dd ] = (_Float16)v;
        } else {
          ((float*)outv)[ (size_t)t*DM + col ] = v;
        }
      }
    }
  }
}

// ---------------- flash attention over 45 KV tiles of 64 ----------------
// one block per (b,h); 8 waves; each wave owns 32 q-rows.
__global__ __launch_bounds__(512) void attn_k(
  const _Float16* __restrict__ qh, const _Float16* __restrict__ kvc,
  const _Float16* __restrict__ vvc, const float* __restrict__ pk,
  const float* __restrict__ pv, const int* __restrict__ pvl,
  const int* __restrict__ cvm, _Float16* __restrict__ aout)
{
  __shared__ __align__(16) _Float16 Ks[64*72];      // [key][d]
  __shared__ __align__(16) _Float16 Vs[64*72];      // transposed: [d][key]
  __shared__ float mk[64];
  __shared__ __align__(16) _Float16 Ps[8][32*72];   // per-wave P round-trip

  const int bh = blockIdx.x;
  const int b = bh >> 4;
  const int h = bh & 15;
  const int tid = threadIdx.x;
  const int lane = tid & 63, wid = tid >> 6;
  const int l15 = lane & 15, l4 = lane >> 4;

  // Q fragments (A-operand): rows 32*wid + rb*16 + l15, k = kc*32 + l4*8 + j
  half8 aq[2][2];
  {
    const _Float16* qb = qh + ((size_t)bh*LQ + wid*32)*HD;
    #pragma unroll
    for (int rb=0;rb<2;++rb)
      #pragma unroll
      for (int kc=0;kc<2;++kc)
        aq[rb][kc] = *(const half8*)(qb + (rb*16+l15)*HD + kc*32 + l4*8);
  }

  f32x4 accO[2][4] = {};
  float mrun[2][4], lrun[2][4];
  #pragma unroll
  for (int rb=0;rb<2;++rb)
    #pragma unroll
    for (int r=0;r<4;++r){ mrun[rb][r] = -3.0e38f; lrun[rb][r] = 0.f; }

  const int skey = tid >> 3;        // 0..63
  const int sd   = (tid & 7) * 8;   // 0..56
  const int myvl = pvl[b];

  for (int kt=0; kt<45; ++kt) {
    __syncthreads();
    if (kt < 9 || kt >= 41) {
      // fp16 K/V from ws (vis or cur)
      const int s = (kt < 9) ? kt*64 : LV + (kt-41)*64;
      const _Float16* kp = kvc + ((size_t)bh*KVC + s)*HD;
      const _Float16* vp = vvc + ((size_t)bh*KVC + s)*HD;
      half8 kx = *(const half8*)(kp + skey*HD + sd);
      half8 vx = *(const half8*)(vp + skey*HD + sd);
      *(half8*)&Ks[skey*72 + sd] = kx;
      #pragma unroll
      for (int j=0;j<8;++j) Vs[(sd+j)*72 + skey] = vx[j];
      if (tid < 64) {
        float m = 0.f;
        if (kt >= 41) m = cvm[b*LC + (s - LV) + tid] ? 0.f : -1e30f;
        mk[tid] = m;
      }
    } else {
      // fp32 past K/V, convert on the fly
      const int s = (kt-9)*64;
      const float* kp = pk + ((size_t)bh*PP + s)*HD;
      const float* vp = pv + ((size_t)bh*PP + s)*HD;
      f32x4 k0 = *(const f32x4*)(kp + skey*HD + sd);
      f32x4 k1 = *(const f32x4*)(kp + skey*HD + sd + 4);
      f32x4 v0 = *(const f32x4*)(vp + skey*HD + sd);
      f32x4 v1 = *(const f32x4*)(vp + skey*HD + sd + 4);
      half8 kx;
      #pragma unroll
      for (int i=0;i<4;++i){ kx[i] = (_Float16)k0[i]; kx[4+i] = (_Float16)k1[i]; }
      *(half8*)&Ks[skey*72 + sd] = kx;
      #pragma unroll
      for (int j=0;j<4;++j) Vs[(sd+j)*72 + skey]   = (_Float16)v0[j];
      #pragma unroll
      for (int j=0;j<4;++j) Vs[(sd+4+j)*72 + skey] = (_Float16)v1[j];
      if (tid < 64) mk[tid] = (s + tid < myvl) ? 0.f : -1e30f;
    }
    __syncthreads();

    // S = Q K^T  (per wave: 32 rows x 64 keys)
    half8 bk[4][2];
    #pragma unroll
    for (int nf=0;nf<4;++nf)
      #pragma unroll
      for (int kc=0;kc<2;++kc)
        bk[nf][kc] = *(const half8*)&Ks[(nf*16+l15)*72 + kc*32 + l4*8];
    f32x4 sf[2][4] = {};
    #pragma unroll
    for (int rb=0;rb<2;++rb)
      #pragma unroll
      for (int nf=0;nf<4;++nf)
        #pragma unroll
        for (int kc=0;kc<2;++kc)
          sf[rb][nf] = MFMA16(aq[rb][kc], bk[nf][kc], sf[rb][nf]);

    float mc[4];
    #pragma unroll
    for (int nf=0;nf<4;++nf) mc[nf] = mk[nf*16 + l15];
    #pragma unroll
    for (int rb=0;rb<2;++rb)
      #pragma unroll
      for (int nf=0;nf<4;++nf)
        #pragma unroll
        for (int r=0;r<4;++r)
          sf[rb][nf][r] = sf[rb][nf][r]*SCALE + mc[nf];

    // online softmax per row (row = l4*4+r within rb-block; cols spread over l15 x nf)
    #pragma unroll
    for (int rb=0;rb<2;++rb)
      #pragma unroll
      for (int r=0;r<4;++r) {
        float mx = fmaxf(fmaxf(sf[rb][0][r],sf[rb][1][r]), fmaxf(sf[rb][2][r],sf[rb][3][r]));
        mx = fmaxf(mx, __shfl_xor(mx,1));
        mx = fmaxf(mx, __shfl_xor(mx,2));
        mx = fmaxf(mx, __shfl_xor(mx,4));
        mx = fmaxf(mx, __shfl_xor(mx,8));
        const float mn = fmaxf(mrun[rb][r], mx);
        const float al = __expf(mrun[rb][r] - mn);
        float rs = 0.f;
        #pragma unroll
        for (int nf=0;nf<4;++nf){ float p = __expf(sf[rb][nf][r]-mn); sf[rb][nf][r]=p; rs+=p; }
        rs += __shfl_xor(rs,1);
        rs += __shfl_xor(rs,2);
        rs += __shfl_xor(rs,4);
        rs += __shfl_xor(rs,8);
        lrun[rb][r] = lrun[rb][r]*al + rs;
        mrun[rb][r] = mn;
        #pragma unroll
        for (int df=0;df<4;++df) accO[rb][df][r] *= al;
      }

    // P round-trip through per-wave LDS to re-layout D-frag -> A-frag
    _Float16* pw = &Ps[wid][0];
    #pragma unroll
    for (int rb=0;rb<2;++rb)
      #pragma unroll
      for (int nf=0;nf<4;++nf)
        #pragma unroll
        for (int r=0;r<4;++r)
          pw[(rb*16 + l4*4 + r)*72 + nf*16 + l15] = (_Float16)sf[rb][nf][r];

    half8 ap[2][2];
    #pragma unroll
    for (int rb=0;rb<2;++rb)
      #pragma unroll
      for (int kc=0;kc<2;++kc)
        ap[rb][kc] = *(const half8*)&pw[(rb*16+l15)*72 + kc*32 + l4*8];

    half8 bvv[4][2];
    #pragma unroll
    for (int df=0;df<4;++df)
      #pragma unroll
      for (int kc=0;kc<2;++kc)
        bvv[df][kc] = *(const half8*)&Vs[(df*16+l15)*72 + kc*32 + l4*8];

    #pragma unroll
    for (int rb=0;rb<2;++rb)
      #pragma unroll
      for (int df=0;df<4;++df)
        #pragma unroll
        for (int kc=0;kc<2;++kc)
          accO[rb][df] = MFMA16(ap[rb][kc], bvv[df][kc], accO[rb][df]);
  }

  // epilogue: normalize and write merged-head fp16 [B*Lq, 1024]
  #pragma unroll
  for (int rb=0;rb<2;++rb)
    #pragma unroll
    for (int r=0;r<4;++r) {
      const float inv = 1.f / lrun[rb][r];
      const int row = wid*32 + rb*16 + l4*4 + r;
      #pragma unroll
      for (int df=0;df<4;++df)
        aout[((size_t)b*LQ + row)*DM + h*HD + df*16 + l15] =
            (_Float16)(accO[rb][df][r]*inv);
    }
}

extern "C" void kernel_launch(void* const* d_in, const int* in_sizes, int n_in,
                              void* d_out, int out_size, void* d_ws, size_t ws_size,
                              hipStream_t stream)
{
  const float* qin = (const float*)d_in[0];
  const float* vis = (const float*)d_in[1];
  const float* pk  = (const float*)d_in[2];
  const float* pv  = (const float*)d_in[3];
  const int*   pvl = (const int*)d_in[4];
  const float* cur = (const float*)d_in[5];
  const int*   cvm = (const int*)d_in[6];
  const float* Wq = (const float*)d_in[7];  const float* bq = (const float*)d_in[8];
  const float* Wk = (const float*)d_in[9];  const float* bk = (const float*)d_in[10];
  const float* Wv = (const float*)d_in[11]; const float* bv = (const float*)d_in[12];
  const float* Wo = (const float*)d_in[13]; const float* bo = (const float*)d_in[14];

  char* ws = (char*)d_ws;
  _Float16* Wtq  = (_Float16*)(ws + ((size_t) 0<<20));   // 2 MB each
  _Float16* Wtk  = (_Float16*)(ws + ((size_t) 2<<20));
  _Float16* Wtv  = (_Float16*)(ws + ((size_t) 4<<20));
  _Float16* Wto  = (_Float16*)(ws + ((size_t) 6<<20));
  _Float16* qhp  = (_Float16*)(ws + ((size_t) 8<<20));   // [B,H,256,64]  4 MB
  _Float16* kvcp = (_Float16*)(ws + ((size_t)12<<20));   // [B,H,832,64] 13 MB
  _Float16* vvcp = (_Float16*)(ws + ((size_t)26<<20));   // [B,H,832,64] 13 MB
  _Float16* aoutp= (_Float16*)(ws + ((size_t)40<<20));   // [B*256,1024]  4 MB

  wtrans_k<<<dim3(16,16,4), 256, 0, stream>>>(Wq,Wk,Wv,Wo, Wtq,Wtk,Wtv,Wto);

  gemm_k<false,0><<<dim3(16,8), 256, 0, stream>>>(qin, Wtq, bq, qhp,  LQ, 0,  LQ);
  gemm_k<false,0><<<dim3(36,8), 256, 0, stream>>>(vis, Wtk, bk, kvcp, LV, 0,  KVC);
  gemm_k<false,0><<<dim3(36,8), 256, 0, stream>>>(vis, Wtv, bv, vvcp, LV, 0,  KVC);
  gemm_k<false,0><<<dim3(16,8), 256, 0, stream>>>(cur, Wtk, bk, kvcp, LC, LV, KVC);
  gemm_k<false,0><<<dim3(16,8), 256, 0, stream>>>(cur, Wtv, bv, vvcp, LC, LV, KVC);

  attn_k<<<dim3(128), 512, 0, stream>>>(qhp, kvcp, vvcp, pk, pv, pvl, cvm, aoutp);

  gemm_k<true,1><<<dim3(16,8), 256, 0, stream>>>(aoutp, Wto, bo, d_out, 1, 0, 0);
}

// Round 5
// 379.331 us; speedup vs baseline: 1.4325x; 1.4325x over previous
//
#include <hip/hip_runtime.h>

using half8 = __attribute__((ext_vector_type(8))) _Float16;
using f32x4 = __attribute__((ext_vector_type(4))) float;

#define MFMA16(a,b,c) __builtin_amdgcn_mfma_f32_16x16x32_f16((a),(b),(c),0,0,0)

constexpr int DM = 1024;
constexpr int NH = 16;
constexpr int HD = 64;
constexpr int LQ = 256, LV = 576, PP = 2048, LC = 256;
constexpr int KVC = LV + LC;            // 832 (vis rows 0..575, cur rows 576..831)
constexpr int NTILES = 45;              // 9 vis + 32 past + 4 cur, 64 keys each
constexpr int NSPLIT = 4;
constexpr int TPC = 12;                 // tiles per chunk (last chunk gets 9)

// ---------------- W -> W^T fp16 (4 matrices) ----------------
__global__ __launch_bounds__(256) void wtrans_k(
    const float* __restrict__ W0, const float* __restrict__ W1,
    const float* __restrict__ W2, const float* __restrict__ W3,
    _Float16* __restrict__ T0, _Float16* __restrict__ T1,
    _Float16* __restrict__ T2, _Float16* __restrict__ T3)
{
  __shared__ float t[64][65];
  const float* W = blockIdx.z==0 ? W0 : blockIdx.z==1 ? W1 : blockIdx.z==2 ? W2 : W3;
  _Float16*   T  = blockIdx.z==0 ? T0 : blockIdx.z==1 ? T1 : blockIdx.z==2 ? T2 : T3;
  const int k0 = blockIdx.x*64, n0 = blockIdx.y*64;
  const int r = threadIdx.x >> 2, c0 = (threadIdx.x & 3)*16;
  const float* src = W + (size_t)(k0+r)*DM + n0 + c0;
  #pragma unroll
  for (int j=0;j<4;++j) {
    f32x4 v = *(const f32x4*)(src + 4*j);
    #pragma unroll
    for (int i=0;i<4;++i) t[r][c0+4*j+i] = v[i];
  }
  __syncthreads();
  half8 o0, o1;
  #pragma unroll
  for (int i=0;i<8;++i) { o0[i] = (_Float16)t[c0+i][r]; o1[i] = (_Float16)t[c0+8+i][r]; }
  _Float16* dst = T + (size_t)(n0+r)*DM + k0 + c0;
  *(half8*)dst = o0;
  *(half8*)(dst+8) = o1;
}

// ---------------- shared 128x128 NT GEMM body ----------------
// AF16: A fp16 (else fp32, converted). MODE 0: fp16 head-split out; MODE 1: fp32 flat out.
template<bool AF16, int MODE>
__device__ __forceinline__ void gemm_body(
    const void* __restrict__ Av, const _Float16* __restrict__ Wt,
    const float* __restrict__ bias, void* __restrict__ outv,
    int L, int off, int LK, int m0, int n0)
{
  __shared__ __align__(16) _Float16 As[128*40];
  __shared__ __align__(16) _Float16 Bs[128*40];
  const int tid = threadIdx.x;
  const int lane = tid & 63, wid = tid >> 6;
  const int l15 = lane & 15, l4 = lane >> 4;
  const int wm = wid >> 1, wn = wid & 1;           // 2x2 waves, 64x64 each
  const int sr = tid >> 1, sc = (tid & 1)*16;      // staging: row 0..127, k-offset 0/16

  _Float16 hv[16], wv[16];

  auto loadT = [&](int kt) {
    if constexpr (AF16) {
      const _Float16* ap = (const _Float16*)Av + (size_t)(m0+sr)*DM + kt*32 + sc;
      half8 x = *(const half8*)ap, y = *(const half8*)(ap+8);
      #pragma unroll
      for (int i=0;i<8;++i){ hv[i]=x[i]; hv[8+i]=y[i]; }
    } else {
      const float* ap = (const float*)Av + (size_t)(m0+sr)*DM + kt*32 + sc;
      #pragma unroll
      for (int j=0;j<4;++j){
        f32x4 v = *(const f32x4*)(ap+4*j);
        #pragma unroll
        for (int i=0;i<4;++i) hv[4*j+i] = (_Float16)v[i];
      }
    }
    const _Float16* wp = Wt + (size_t)(n0+sr)*DM + kt*32 + sc;
    half8 x = *(const half8*)wp, y = *(const half8*)(wp+8);
    #pragma unroll
    for (int i=0;i<8;++i){ wv[i]=x[i]; wv[8+i]=y[i]; }
  };

  f32x4 acc[4][4] = {};
  loadT(0);

  for (int kt=0; kt<32; ++kt) {
    __syncthreads();
    {
      half8 a0,a1,b0,b1;
      #pragma unroll
      for (int i=0;i<8;++i){ a0[i]=hv[i]; a1[i]=hv[8+i]; b0[i]=wv[i]; b1[i]=wv[8+i]; }
      *(half8*)&As[sr*40+sc]   = a0;
      *(half8*)&As[sr*40+sc+8] = a1;
      *(half8*)&Bs[sr*40+sc]   = b0;
      *(half8*)&Bs[sr*40+sc+8] = b1;
    }
    __syncthreads();
    if (kt < 31) loadT(kt+1);   // overlap next-tile global loads with compute

    half8 af[4], bf[4];
    #pragma unroll
    for (int mf=0;mf<4;++mf) af[mf] = *(const half8*)&As[(wm*64+mf*16+l15)*40 + l4*8];
    #pragma unroll
    for (int nf=0;nf<4;++nf) bf[nf] = *(const half8*)&Bs[(wn*64+nf*16+l15)*40 + l4*8];
    #pragma unroll
    for (int mf=0;mf<4;++mf)
      #pragma unroll
      for (int nf=0;nf<4;++nf)
        acc[mf][nf] = MFMA16(af[mf], bf[nf], acc[mf][nf]);
  }

  #pragma unroll
  for (int nf=0;nf<4;++nf) {
    const int col = n0 + wn*64 + nf*16 + l15;
    const float bv = bias[col];
    const int hh = col >> 6, dd = col & 63;
    #pragma unroll
    for (int mf=0;mf<4;++mf) {
      const int rbase = m0 + wm*64 + mf*16 + l4*4;
      #pragma unroll
      for (int r=0;r<4;++r) {
        const int t = rbase + r;
        const float v = acc[mf][nf][r] + bv;
        if constexpr (MODE==0) {
          const int bb = t / L, pos = t - bb*L;
          ((_Float16*)outv)[ ((size_t)((bb*NH + hh)*LK + off + pos))*HD + dd ] = (_Float16)v;
        } else {
          ((float*)outv)[ (size_t)t*DM + col ] = v;
        }
      }
    }
  }
}

// ---------------- fused QKV projection: one launch, 3 row-segments x {Q | K,V} ----------------
// grid (68,16): x<16 -> qin rows (y<8 only, Wq); x in [16,52) -> vis rows; x >= 52 -> cur rows.
// y<8 -> K (or Q) cols; y>=8 -> V cols.
__global__ __launch_bounds__(256) void proj_k(
    const float* __restrict__ qin, const float* __restrict__ vis, const float* __restrict__ cur,
    const _Float16* __restrict__ Wtq, const _Float16* __restrict__ Wtk, const _Float16* __restrict__ Wtv,
    const float* __restrict__ bq, const float* __restrict__ bk, const float* __restrict__ bv,
    _Float16* __restrict__ qhp, _Float16* __restrict__ kvcp, _Float16* __restrict__ vvcp)
{
  const int bx = blockIdx.x, by = blockIdx.y;
  const float* A; const _Float16* Wt; const float* bias; _Float16* out;
  int m0, n0, L, off, LK;
  if (bx < 16) {
    if (by >= 8) return;                 // q-proj has only 1024 output cols
    A = qin; m0 = bx*128; L = LQ; off = 0; LK = LQ;
    Wt = Wtq; bias = bq; out = qhp; n0 = by*128;
  } else {
    if (bx < 52) { A = vis; m0 = (bx-16)*128; L = LV; off = 0; }
    else         { A = cur; m0 = (bx-52)*128; L = LC; off = LV; }
    LK = KVC;
    if (by < 8) { Wt = Wtk; bias = bk; out = kvcp; n0 = by*128; }
    else        { Wt = Wtv; bias = bv; out = vvcp; n0 = (by-8)*128; }
  }
  gemm_body<false,0>(A, Wt, bias, out, L, off, LK, m0, n0);
}

// ---------------- output projection ----------------
__global__ __launch_bounds__(256) void gemmo_k(
    const _Float16* __restrict__ A, const _Float16* __restrict__ Wt,
    const float* __restrict__ bias, float* __restrict__ out)
{
  gemm_body<true,1>(A, Wt, bias, out, 1, 0, 0, blockIdx.x*128, blockIdx.y*128);
}

// ---------------- flash attention, KV-split into NSPLIT chunks ----------------
// grid (128, NSPLIT); block 512 = 8 waves x 32 q-rows. Register-prefetch double buffer.
// Writes unnormalized partial O (fp32) + per-row running (m,l).
__global__ __launch_bounds__(512) void attn_k(
  const _Float16* __restrict__ qh, const _Float16* __restrict__ kvc,
  const _Float16* __restrict__ vvc, const float* __restrict__ pk,
  const float* __restrict__ pv, const int* __restrict__ pvl,
  const int* __restrict__ cvm, float* __restrict__ Opart,
  float* __restrict__ mpart, float* __restrict__ lpart)
{
  __shared__ __align__(16) _Float16 Ks[64*72];      // [key][d]
  __shared__ __align__(16) _Float16 Vs[64*72];      // transposed: [d][key]
  __shared__ float mk[64];
  __shared__ __align__(16) _Float16 Ps[8][32*72];   // per-wave P round-trip

  const int bh = blockIdx.x;
  const int ck = blockIdx.y;
  const int b = bh >> 4;
  const int tid = threadIdx.x;
  const int lane = tid & 63, wid = tid >> 6;
  const int l15 = lane & 15, l4 = lane >> 4;

  const int kt0 = ck*TPC;
  const int kt1 = (kt0 + TPC < NTILES) ? kt0 + TPC : NTILES;

  // Q fragments, pre-scaled by 1/sqrt(64) (exact power of 2 in fp16)
  half8 aq[2][2];
  {
    const _Float16* qb = qh + ((size_t)bh*LQ + wid*32)*HD;
    #pragma unroll
    for (int rb=0;rb<2;++rb)
      #pragma unroll
      for (int kc=0;kc<2;++kc) {
        half8 x = *(const half8*)(qb + (rb*16+l15)*HD + kc*32 + l4*8);
        #pragma unroll
        for (int j=0;j<8;++j) x[j] = x[j] * (_Float16)0.125f;
        aq[rb][kc] = x;
      }
  }

  f32x4 accO[2][4] = {};
  float mrun[2][4], lrun[2][4];
  #pragma unroll
  for (int rb=0;rb<2;++rb)
    #pragma unroll
    for (int r=0;r<4;++r){ mrun[rb][r] = -3.0e38f; lrun[rb][r] = 0.f; }

  const int skey = tid >> 3;        // 0..63
  const int sd   = (tid & 7) * 8;   // 0..56
  const int myvl = pvl[b];

  // prefetch registers
  half8 kreg, vreg;                 // fp16 sources
  f32x4 k0r, k1r, v0r, v1r;         // fp32 past sources
  float mreg = 0.f;

  auto prefetch = [&](int kt) {
    if (kt < 9 || kt >= 41) {
      const int s = (kt < 9) ? kt*64 : LV + (kt-41)*64;
      const _Float16* kp = kvc + ((size_t)bh*KVC + s)*HD;
      const _Float16* vp = vvc + ((size_t)bh*KVC + s)*HD;
      kreg = *(const half8*)(kp + skey*HD + sd);
      vreg = *(const half8*)(vp + skey*HD + sd);
      if (tid < 64) mreg = (kt >= 41) ? (cvm[b*LC + (s - LV) + tid] ? 0.f : -1e30f) : 0.f;
    } else {
      const int s = (kt-9)*64;
      const float* kp = pk + ((size_t)bh*PP + s)*HD;
      const float* vp = pv + ((size_t)bh*PP + s)*HD;
      k0r = *(const f32x4*)(kp + skey*HD + sd);
      k1r = *(const f32x4*)(kp + skey*HD + sd + 4);
      v0r = *(const f32x4*)(vp + skey*HD + sd);
      v1r = *(const f32x4*)(vp + skey*HD + sd + 4);
      if (tid < 64) mreg = (s + tid < myvl) ? 0.f : -1e30f;
    }
  };

  prefetch(kt0);

  for (int kt=kt0; kt<kt1; ++kt) {
    __syncthreads();                      // prior compute done reading LDS
    if (kt < 9 || kt >= 41) {
      *(half8*)&Ks[skey*72 + sd] = kreg;
      #pragma unroll
      for (int j=0;j<8;++j) Vs[(sd+j)*72 + skey] = vreg[j];
    } else {
      half8 kx;
      #pragma unroll
      for (int i=0;i<4;++i){ kx[i] = (_Float16)k0r[i]; kx[4+i] = (_Float16)k1r[i]; }
      *(half8*)&Ks[skey*72 + sd] = kx;
      #pragma unroll
      for (int j=0;j<4;++j) Vs[(sd+j)*72 + skey]   = (_Float16)v0r[j];
      #pragma unroll
      for (int j=0;j<4;++j) Vs[(sd+4+j)*72 + skey] = (_Float16)v1r[j];
    }
    if (tid < 64) mk[tid] = mreg;
    __syncthreads();
    if (kt+1 < kt1) prefetch(kt+1);       // global loads fly under the MFMA work below

    // S = Q K^T (pre-scaled)
    half8 bk_[4][2];
    #pragma unroll
    for (int nf=0;nf<4;++nf)
      #pragma unroll
      for (int kc=0;kc<2;++kc)
        bk_[nf][kc] = *(const half8*)&Ks[(nf*16+l15)*72 + kc*32 + l4*8];
    f32x4 sf[2][4] = {};
    #pragma unroll
    for (int rb=0;rb<2;++rb)
      #pragma unroll
      for (int nf=0;nf<4;++nf)
        #pragma unroll
        for (int kc=0;kc<2;++kc)
          sf[rb][nf] = MFMA16(aq[rb][kc], bk_[nf][kc], sf[rb][nf]);

    float mc[4];
    #pragma unroll
    for (int nf=0;nf<4;++nf) mc[nf] = mk[nf*16 + l15];
    #pragma unroll
    for (int rb=0;rb<2;++rb)
      #pragma unroll
      for (int nf=0;nf<4;++nf)
        #pragma unroll
        for (int r=0;r<4;++r)
          sf[rb][nf][r] += mc[nf];

    // online softmax per row
    #pragma unroll
    for (int rb=0;rb<2;++rb)
      #pragma unroll
      for (int r=0;r<4;++r) {
        float mx = fmaxf(fmaxf(sf[rb][0][r],sf[rb][1][r]), fmaxf(sf[rb][2][r],sf[rb][3][r]));
        mx = fmaxf(mx, __shfl_xor(mx,1));
        mx = fmaxf(mx, __shfl_xor(mx,2));
        mx = fmaxf(mx, __shfl_xor(mx,4));
        mx = fmaxf(mx, __shfl_xor(mx,8));
        const float mn = fmaxf(mrun[rb][r], mx);
        const float al = __expf(mrun[rb][r] - mn);
        float rs = 0.f;
        #pragma unroll
        for (int nf=0;nf<4;++nf){ float p = __expf(sf[rb][nf][r]-mn); sf[rb][nf][r]=p; rs+=p; }
        rs += __shfl_xor(rs,1);
        rs += __shfl_xor(rs,2);
        rs += __shfl_xor(rs,4);
        rs += __shfl_xor(rs,8);
        lrun[rb][r] = lrun[rb][r]*al + rs;
        mrun[rb][r] = mn;
        #pragma unroll
        for (int df=0;df<4;++df) accO[rb][df][r] *= al;
      }

    // P round-trip through per-wave LDS (D-frag -> A-frag)
    _Float16* pw = &Ps[wid][0];
    #pragma unroll
    for (int rb=0;rb<2;++rb)
      #pragma unroll
      for (int nf=0;nf<4;++nf)
        #pragma unroll
        for (int r=0;r<4;++r)
          pw[(rb*16 + l4*4 + r)*72 + nf*16 + l15] = (_Float16)sf[rb][nf][r];

    half8 ap[2][2];
    #pragma unroll
    for (int rb=0;rb<2;++rb)
      #pragma unroll
      for (int kc=0;kc<2;++kc)
        ap[rb][kc] = *(const half8*)&pw[(rb*16+l15)*72 + kc*32 + l4*8];

    half8 bvv[4][2];
    #pragma unroll
    for (int df=0;df<4;++df)
      #pragma unroll
      for (int kc=0;kc<2;++kc)
        bvv[df][kc] = *(const half8*)&Vs[(df*16+l15)*72 + kc*32 + l4*8];

    #pragma unroll
    for (int rb=0;rb<2;++rb)
      #pragma unroll
      for (int df=0;df<4;++df)
        #pragma unroll
        for (int kc=0;kc<2;++kc)
          accO[rb][df] = MFMA16(ap[rb][kc], bvv[df][kc], accO[rb][df]);
  }

  // epilogue: write unnormalized partials + (m,l)
  const int base = (ck*128 + bh) * LQ;
  #pragma unroll
  for (int rb=0;rb<2;++rb)
    #pragma unroll
    for (int r=0;r<4;++r) {
      const int row = wid*32 + rb*16 + l4*4 + r;
      #pragma unroll
      for (int df=0;df<4;++df)
        Opart[((size_t)(base + row))*HD + df*16 + l15] = accO[rb][df][r];
      if (l15 == 0) {
        mpart[base + row] = mrun[rb][r];
        lpart[base + row] = lrun[rb][r];
      }
    }
}

// ---------------- combine NSPLIT partials -> merged-head fp16 [B*Lq, 1024] ----------------
__global__ __launch_bounds__(256) void combine_k(
    const float* __restrict__ Opart, const float* __restrict__ mpart,
    const float* __restrict__ lpart, _Float16* __restrict__ aout)
{
  const int t = blockIdx.x*256 + threadIdx.x;    // 524288 threads
  const int rg = t >> 4;                          // global row 0..32767
  const int d0 = (t & 15) * 4;
  const int bh = rg >> 8, qr = rg & 255;
  const int b = bh >> 4, h = bh & 15;

  float m[NSPLIT], l[NSPLIT];
  float mstar = -3.0e38f;
  #pragma unroll
  for (int c=0;c<NSPLIT;++c) {
    m[c] = mpart[(c*128 + bh)*LQ + qr];
    l[c] = lpart[(c*128 + bh)*LQ + qr];
    mstar = fmaxf(mstar, m[c]);
  }
  float lsum = 0.f, w[NSPLIT];
  #pragma unroll
  for (int c=0;c<NSPLIT;++c) { w[c] = __expf(m[c]-mstar); lsum += l[c]*w[c]; }
  const float inv = 1.f / lsum;

  f32x4 o = {};
  #pragma unroll
  for (int c=0;c<NSPLIT;++c) {
    f32x4 x = *(const f32x4*)&Opart[((size_t)((c*128 + bh)*LQ + qr))*HD + d0];
    #pragma unroll
    for (int i=0;i<4;++i) o[i] += x[i]*w[c];
  }
  _Float16* dst = aout + ((size_t)(b*LQ + qr))*DM + h*HD + d0;
  #pragma unroll
  for (int i=0;i<4;++i) dst[i] = (_Float16)(o[i]*inv);
}

extern "C" void kernel_launch(void* const* d_in, const int* in_sizes, int n_in,
                              void* d_out, int out_size, void* d_ws, size_t ws_size,
                              hipStream_t stream)
{
  const float* qin = (const float*)d_in[0];
  const float* vis = (const float*)d_in[1];
  const float* pk  = (const float*)d_in[2];
  const float* pv  = (const float*)d_in[3];
  const int*   pvl = (const int*)d_in[4];
  const float* cur = (const float*)d_in[5];
  const int*   cvm = (const int*)d_in[6];
  const float* Wq = (const float*)d_in[7];  const float* bq = (const float*)d_in[8];
  const float* Wk = (const float*)d_in[9];  const float* bk = (const float*)d_in[10];
  const float* Wv = (const float*)d_in[11]; const float* bv = (const float*)d_in[12];
  const float* Wo = (const float*)d_in[13]; const float* bo = (const float*)d_in[14];

  char* ws = (char*)d_ws;
  _Float16* Wtq  = (_Float16*)(ws + ((size_t) 0<<20));   // 2 MB each
  _Float16* Wtk  = (_Float16*)(ws + ((size_t) 2<<20));
  _Float16* Wtv  = (_Float16*)(ws + ((size_t) 4<<20));
  _Float16* Wto  = (_Float16*)(ws + ((size_t) 6<<20));
  _Float16* qhp  = (_Float16*)(ws + ((size_t) 8<<20));   // [B,H,256,64]  4 MB
  _Float16* kvcp = (_Float16*)(ws + ((size_t)12<<20));   // [B,H,832,64] 13.6 MB
  _Float16* vvcp = (_Float16*)(ws + ((size_t)26<<20));   // [B,H,832,64] 13.6 MB
  _Float16* aoutp= (_Float16*)(ws + ((size_t)40<<20));   // [B*256,1024]  4 MB
  float*    Opart= (float*)   (ws + ((size_t)45<<20));   // [4,128,256,64] f32 33.6 MB
  float*    mpart= (float*)   (ws + ((size_t)79<<20));   // [4,128,256] f32 0.5 MB
  float*    lpart= (float*)   (ws + ((size_t)79<<20) + 524288);

  wtrans_k<<<dim3(16,16,4), 256, 0, stream>>>(Wq,Wk,Wv,Wo, Wtq,Wtk,Wtv,Wto);

  proj_k<<<dim3(68,16), 256, 0, stream>>>(qin, vis, cur, Wtq, Wtk, Wtv,
                                          bq, bk, bv, qhp, kvcp, vvcp);

  attn_k<<<dim3(128,NSPLIT), 512, 0, stream>>>(qhp, kvcp, vvcp, pk, pv, pvl, cvm,
                                               Opart, mpart, lpart);

  combine_k<<<dim3(2048), 256, 0, stream>>>(Opart, mpart, lpart, aoutp);

  gemmo_k<<<dim3(16,8), 256, 0, stream>>>(aoutp, Wto, bo, (float*)d_out);
}

// Round 6
// 351.363 us; speedup vs baseline: 1.5465x; 1.0796x over previous
//
#include <hip/hip_runtime.h>

using half8 = __attribute__((ext_vector_type(8))) _Float16;
using f32x4 = __attribute__((ext_vector_type(4))) float;

#define MFMA16(a,b,c) __builtin_amdgcn_mfma_f32_16x16x32_f16((a),(b),(c),0,0,0)

constexpr int DM = 1024;
constexpr int NH = 16;
constexpr int HD = 64;
constexpr int LQ = 256, LV = 576, PP = 2048, LC = 256;
constexpr int KVC = LV + LC;            // 832 (vis rows 0..575, cur rows 576..831)
constexpr int NSPLIT = 8;

// ---------------- W -> W^T fp16 (4 matrices) ----------------
__global__ __launch_bounds__(256) void wtrans_k(
    const float* __restrict__ W0, const float* __restrict__ W1,
    const float* __restrict__ W2, const float* __restrict__ W3,
    _Float16* __restrict__ T0, _Float16* __restrict__ T1,
    _Float16* __restrict__ T2, _Float16* __restrict__ T3)
{
  __shared__ float t[64][65];
  const float* W = blockIdx.z==0 ? W0 : blockIdx.z==1 ? W1 : blockIdx.z==2 ? W2 : W3;
  _Float16*   T  = blockIdx.z==0 ? T0 : blockIdx.z==1 ? T1 : blockIdx.z==2 ? T2 : T3;
  const int k0 = blockIdx.x*64, n0 = blockIdx.y*64;
  const int r = threadIdx.x >> 2, c0 = (threadIdx.x & 3)*16;
  const float* src = W + (size_t)(k0+r)*DM + n0 + c0;
  #pragma unroll
  for (int j=0;j<4;++j) {
    f32x4 v = *(const f32x4*)(src + 4*j);
    #pragma unroll
    for (int i=0;i<4;++i) t[r][c0+4*j+i] = v[i];
  }
  __syncthreads();
  half8 o0, o1;
  #pragma unroll
  for (int i=0;i<8;++i) { o0[i] = (_Float16)t[c0+i][r]; o1[i] = (_Float16)t[c0+8+i][r]; }
  _Float16* dst = T + (size_t)(n0+r)*DM + k0 + c0;
  *(half8*)dst = o0;
  *(half8*)(dst+8) = o1;
}

// ---------------- shared 128x128 NT GEMM body ----------------
template<bool AF16, int MODE>
__device__ __forceinline__ void gemm_body(
    const void* __restrict__ Av, const _Float16* __restrict__ Wt,
    const float* __restrict__ bias, void* __restrict__ outv,
    int L, int off, int LK, int m0, int n0)
{
  __shared__ __align__(16) _Float16 As[128*40];
  __shared__ __align__(16) _Float16 Bs[128*40];
  const int tid = threadIdx.x;
  const int lane = tid & 63, wid = tid >> 6;
  const int l15 = lane & 15, l4 = lane >> 4;
  const int wm = wid >> 1, wn = wid & 1;           // 2x2 waves, 64x64 each
  const int sr = tid >> 1, sc = (tid & 1)*16;      // staging: row 0..127, k-offset 0/16

  _Float16 hv[16], wv[16];

  auto loadT = [&](int kt) {
    if constexpr (AF16) {
      const _Float16* ap = (const _Float16*)Av + (size_t)(m0+sr)*DM + kt*32 + sc;
      half8 x = *(const half8*)ap, y = *(const half8*)(ap+8);
      #pragma unroll
      for (int i=0;i<8;++i){ hv[i]=x[i]; hv[8+i]=y[i]; }
    } else {
      const float* ap = (const float*)Av + (size_t)(m0+sr)*DM + kt*32 + sc;
      #pragma unroll
      for (int j=0;j<4;++j){
        f32x4 v = *(const f32x4*)(ap+4*j);
        #pragma unroll
        for (int i=0;i<4;++i) hv[4*j+i] = (_Float16)v[i];
      }
    }
    const _Float16* wp = Wt + (size_t)(n0+sr)*DM + kt*32 + sc;
    half8 x = *(const half8*)wp, y = *(const half8*)(wp+8);
    #pragma unroll
    for (int i=0;i<8;++i){ wv[i]=x[i]; wv[8+i]=y[i]; }
  };

  f32x4 acc[4][4] = {};
  loadT(0);

  for (int kt=0; kt<32; ++kt) {
    __syncthreads();
    {
      half8 a0,a1,b0,b1;
      #pragma unroll
      for (int i=0;i<8;++i){ a0[i]=hv[i]; a1[i]=hv[8+i]; b0[i]=wv[i]; b1[i]=wv[8+i]; }
      *(half8*)&As[sr*40+sc]   = a0;
      *(half8*)&As[sr*40+sc+8] = a1;
      *(half8*)&Bs[sr*40+sc]   = b0;
      *(half8*)&Bs[sr*40+sc+8] = b1;
    }
    __syncthreads();
    if (kt < 31) loadT(kt+1);

    half8 af[4], bf[4];
    #pragma unroll
    for (int mf=0;mf<4;++mf) af[mf] = *(const half8*)&As[(wm*64+mf*16+l15)*40 + l4*8];
    #pragma unroll
    for (int nf=0;nf<4;++nf) bf[nf] = *(const half8*)&Bs[(wn*64+nf*16+l15)*40 + l4*8];
    #pragma unroll
    for (int mf=0;mf<4;++mf)
      #pragma unroll
      for (int nf=0;nf<4;++nf)
        acc[mf][nf] = MFMA16(af[mf], bf[nf], acc[mf][nf]);
  }

  #pragma unroll
  for (int nf=0;nf<4;++nf) {
    const int col = n0 + wn*64 + nf*16 + l15;
    const float bv = bias[col];
    const int hh = col >> 6, dd = col & 63;
    #pragma unroll
    for (int mf=0;mf<4;++mf) {
      const int rbase = m0 + wm*64 + mf*16 + l4*4;
      #pragma unroll
      for (int r=0;r<4;++r) {
        const int t = rbase + r;
        const float v = acc[mf][nf][r] + bv;
        if constexpr (MODE==0) {
          const int bb = t / L, pos = t - bb*L;
          ((_Float16*)outv)[ ((size_t)((bb*NH + hh)*LK + off + pos))*HD + dd ] = (_Float16)v;
        } else {
          ((float*)outv)[ (size_t)t*DM + col ] = v;
        }
      }
    }
  }
}

// ---------------- fused QKV projection ----------------
__global__ __launch_bounds__(256) void proj_k(
    const float* __restrict__ qin, const float* __restrict__ vis, const float* __restrict__ cur,
    const _Float16* __restrict__ Wtq, const _Float16* __restrict__ Wtk, const _Float16* __restrict__ Wtv,
    const float* __restrict__ bq, const float* __restrict__ bk, const float* __restrict__ bv,
    _Float16* __restrict__ qhp, _Float16* __restrict__ kvcp, _Float16* __restrict__ vvcp)
{
  const int bx = blockIdx.x, by = blockIdx.y;
  const float* A; const _Float16* Wt; const float* bias; _Float16* out;
  int m0, n0, L, off, LK;
  if (bx < 16) {
    if (by >= 8) return;
    A = qin; m0 = bx*128; L = LQ; off = 0; LK = LQ;
    Wt = Wtq; bias = bq; out = qhp; n0 = by*128;
  } else {
    if (bx < 52) { A = vis; m0 = (bx-16)*128; L = LV; off = 0; }
    else         { A = cur; m0 = (bx-52)*128; L = LC; off = LV; }
    LK = KVC;
    if (by < 8) { Wt = Wtk; bias = bk; out = kvcp; n0 = by*128; }
    else        { Wt = Wtv; bias = bv; out = vvcp; n0 = (by-8)*128; }
  }
  gemm_body<false,0>(A, Wt, bias, out, L, off, LK, m0, n0);
}

// ---------------- output projection ----------------
__global__ __launch_bounds__(256) void gemmo_k(
    const _Float16* __restrict__ A, const _Float16* __restrict__ Wt,
    const float* __restrict__ bias, float* __restrict__ out)
{
  gemm_body<true,1>(A, Wt, bias, out, 1, 0, 0, blockIdx.x*128, blockIdx.y*128);
}

// ---------------- flash attention, valid tiles balanced over NSPLIT chunks ----------------
// grid (128, NSPLIT); block 512 = 8 waves x 32 q-rows. Skips fully-masked past tiles.
// V-store XOR-swizzle: Vs[d][key ^ ((d>>3)<<3)] kills the 16-way transpose conflict.
__global__ __launch_bounds__(512) void attn_k(
  const _Float16* __restrict__ qh, const _Float16* __restrict__ kvc,
  const _Float16* __restrict__ vvc, const float* __restrict__ pk,
  const float* __restrict__ pv, const int* __restrict__ pvl,
  const int* __restrict__ cvm, _Float16* __restrict__ Opart,
  float* __restrict__ mpart, float* __restrict__ lpart)
{
  __shared__ __align__(16) _Float16 Ks[64*72];      // [key][d]
  __shared__ __align__(16) _Float16 Vs[64*72];      // [d][key^swz]
  __shared__ float mk[64];
  __shared__ __align__(16) _Float16 Ps[8][16*72];   // per-wave P round-trip (16 rows, 2-step)

  const int bh = blockIdx.x;
  const int ck = blockIdx.y;
  const int b = bh >> 4;
  const int tid = threadIdx.x;
  const int lane = tid & 63, wid = tid >> 6;
  const int l15 = lane & 15, l4 = lane >> 4;

  const int myvl = pvl[b];
  const int vpt = (myvl + 63) >> 6;       // valid past tiles
  const int T = 9 + vpt + 4;              // total valid tiles (13..45)
  const int qn = T >> 3, rr = T & 7;
  const int len = qn + (ck < rr ? 1 : 0);
  const int lo = ck*qn + (ck < rr ? ck : rr);
  const int hi = lo + len;

  // Q fragments, pre-scaled by 1/sqrt(64)
  half8 aq[2][2];
  {
    const _Float16* qb = qh + ((size_t)bh*LQ + wid*32)*HD;
    #pragma unroll
    for (int rb=0;rb<2;++rb)
      #pragma unroll
      for (int kc=0;kc<2;++kc) {
        half8 x = *(const half8*)(qb + (rb*16+l15)*HD + kc*32 + l4*8);
        #pragma unroll
        for (int j=0;j<8;++j) x[j] = x[j] * (_Float16)0.125f;
        aq[rb][kc] = x;
      }
  }

  f32x4 accO[2][4] = {};
  float mrun[2][4], lrun[2][4];
  #pragma unroll
  for (int rb=0;rb<2;++rb)
    #pragma unroll
    for (int r=0;r<4;++r){ mrun[rb][r] = -3.0e38f; lrun[rb][r] = 0.f; }

  const int skey = tid >> 3;              // 0..63
  const int sd   = (tid & 7) * 8;         // 0..56
  const int vswz = (tid & 7) << 3;        // (d>>3)<<3 for this thread's 8 d-rows
  const int skeyv = skey ^ vswz;          // swizzled V column

  // prefetch registers
  half8 kreg, vreg;
  f32x4 k0r, k1r, v0r, v1r;
  float mreg = 0.f;
  int ptype = 0;                          // 0 vis, 1 past, 2 cur

  auto prefetch = [&](int t) {
    int s;
    if (t < 9)            { ptype = 0; s = t*64; }
    else if (t < 9 + vpt) { ptype = 1; s = (t-9)*64; }
    else                  { ptype = 2; s = LV + (t-9-vpt)*64; }
    if (ptype != 1) {
      const _Float16* kp = kvc + ((size_t)bh*KVC + s)*HD;
      const _Float16* vp = vvc + ((size_t)bh*KVC + s)*HD;
      kreg = *(const half8*)(kp + skey*HD + sd);
      vreg = *(const half8*)(vp + skey*HD + sd);
      if (tid < 64) mreg = (ptype==2) ? (cvm[b*LC + (s - LV) + tid] ? 0.f : -1e30f) : 0.f;
    } else {
      const float* kp = pk + ((size_t)bh*PP + s)*HD;
      const float* vp = pv + ((size_t)bh*PP + s)*HD;
      k0r = *(const f32x4*)(kp + skey*HD + sd);
      k1r = *(const f32x4*)(kp + skey*HD + sd + 4);
      v0r = *(const f32x4*)(vp + skey*HD + sd);
      v1r = *(const f32x4*)(vp + skey*HD + sd + 4);
      if (tid < 64) mreg = (s + tid < myvl) ? 0.f : -1e30f;
    }
  };

  prefetch(lo);

  for (int t=lo; t<hi; ++t) {
    __syncthreads();
    if (ptype != 1) {
      *(half8*)&Ks[skey*72 + sd] = kreg;
      #pragma unroll
      for (int j=0;j<8;++j) Vs[(sd+j)*72 + skeyv] = vreg[j];
    } else {
      half8 kx;
      #pragma unroll
      for (int i=0;i<4;++i){ kx[i] = (_Float16)k0r[i]; kx[4+i] = (_Float16)k1r[i]; }
      *(half8*)&Ks[skey*72 + sd] = kx;
      #pragma unroll
      for (int j=0;j<4;++j) Vs[(sd+j)*72 + skeyv]   = (_Float16)v0r[j];
      #pragma unroll
      for (int j=0;j<4;++j) Vs[(sd+4+j)*72 + skeyv] = (_Float16)v1r[j];
    }
    if (tid < 64) mk[tid] = mreg;
    __syncthreads();
    if (t+1 < hi) prefetch(t+1);

    // S = Q K^T (pre-scaled)
    half8 bk_[4][2];
    #pragma unroll
    for (int nf=0;nf<4;++nf)
      #pragma unroll
      for (int kc=0;kc<2;++kc)
        bk_[nf][kc] = *(const half8*)&Ks[(nf*16+l15)*72 + kc*32 + l4*8];
    f32x4 sf[2][4] = {};
    #pragma unroll
    for (int rb=0;rb<2;++rb)
      #pragma unroll
      for (int nf=0;nf<4;++nf)
        #pragma unroll
        for (int kc=0;kc<2;++kc)
          sf[rb][nf] = MFMA16(aq[rb][kc], bk_[nf][kc], sf[rb][nf]);

    float mc[4];
    #pragma unroll
    for (int nf=0;nf<4;++nf) mc[nf] = mk[nf*16 + l15];
    #pragma unroll
    for (int rb=0;rb<2;++rb)
      #pragma unroll
      for (int nf=0;nf<4;++nf)
        #pragma unroll
        for (int r=0;r<4;++r)
          sf[rb][nf][r] += mc[nf];

    // online softmax per row
    #pragma unroll
    for (int rb=0;rb<2;++rb)
      #pragma unroll
      for (int r=0;r<4;++r) {
        float mx = fmaxf(fmaxf(sf[rb][0][r],sf[rb][1][r]), fmaxf(sf[rb][2][r],sf[rb][3][r]));
        mx = fmaxf(mx, __shfl_xor(mx,1));
        mx = fmaxf(mx, __shfl_xor(mx,2));
        mx = fmaxf(mx, __shfl_xor(mx,4));
        mx = fmaxf(mx, __shfl_xor(mx,8));
        const float mn = fmaxf(mrun[rb][r], mx);
        const float al = __expf(mrun[rb][r] - mn);
        float rs = 0.f;
        #pragma unroll
        for (int nf=0;nf<4;++nf){ float p = __expf(sf[rb][nf][r]-mn); sf[rb][nf][r]=p; rs+=p; }
        rs += __shfl_xor(rs,1);
        rs += __shfl_xor(rs,2);
        rs += __shfl_xor(rs,4);
        rs += __shfl_xor(rs,8);
        lrun[rb][r] = lrun[rb][r]*al + rs;
        mrun[rb][r] = mn;
        #pragma unroll
        for (int df=0;df<4;++df) accO[rb][df][r] *= al;
      }

    // V fragments (swizzle-compensated read)
    half8 bvv[4][2];
    #pragma unroll
    for (int df=0;df<4;++df) {
      const int rot = (df*2 + (l15>>3)) & 7;        // (d>>3)&7 for row d=df*16+l15
      #pragma unroll
      for (int kc=0;kc<2;++kc)
        bvv[df][kc] = *(const half8*)&Vs[(df*16+l15)*72 + ((((kc<<2)|l4) ^ rot) << 3)];
    }

    // P round-trip, 16 rows at a time (2 steps)
    _Float16* pw = &Ps[wid][0];
    #pragma unroll
    for (int rb=0;rb<2;++rb) {
      #pragma unroll
      for (int nf=0;nf<4;++nf)
        #pragma unroll
        for (int r=0;r<4;++r)
          pw[(l4*4 + r)*72 + nf*16 + l15] = (_Float16)sf[rb][nf][r];

      half8 ap[2];
      #pragma unroll
      for (int kc=0;kc<2;++kc)
        ap[kc] = *(const half8*)&pw[l15*72 + kc*32 + l4*8];

      #pragma unroll
      for (int df=0;df<4;++df)
        #pragma unroll
        for (int kc=0;kc<2;++kc)
          accO[rb][df] = MFMA16(ap[kc], bvv[df][kc], accO[rb][df]);
    }
  }

  // epilogue: unnormalized fp16 partials + (m,l)
  const int base = (ck*128 + bh) * LQ;
  #pragma unroll
  for (int rb=0;rb<2;++rb)
    #pragma unroll
    for (int r=0;r<4;++r) {
      const int row = wid*32 + rb*16 + l4*4 + r;
      #pragma unroll
      for (int df=0;df<4;++df)
        Opart[((size_t)(base + row))*HD + df*16 + l15] = (_Float16)accO[rb][df][r];
      if (l15 == 0) {
        mpart[base + row] = mrun[rb][r];
        lpart[base + row] = lrun[rb][r];
      }
    }
}

// ---------------- combine NSPLIT partials -> merged-head fp16 [B*Lq, 1024] ----------------
__global__ __launch_bounds__(256) void combine_k(
    const _Float16* __restrict__ Opart, const float* __restrict__ mpart,
    const float* __restrict__ lpart, _Float16* __restrict__ aout)
{
  const int t = blockIdx.x*256 + threadIdx.x;     // 262144 threads
  const int rg = t >> 3;                           // global row 0..32767
  const int d0 = (t & 7) * 8;
  const int bh = rg >> 8, qr = rg & 255;
  const int b = bh >> 4, h = bh & 15;

  float m[NSPLIT], l[NSPLIT];
  float mstar = -3.0e38f;
  #pragma unroll
  for (int c=0;c<NSPLIT;++c) {
    m[c] = mpart[(c*128 + bh)*LQ + qr];
    l[c] = lpart[(c*128 + bh)*LQ + qr];
    mstar = fmaxf(mstar, m[c]);
  }
  float lsum = 0.f, w[NSPLIT];
  #pragma unroll
  for (int c=0;c<NSPLIT;++c) { w[c] = __expf(m[c]-mstar); lsum += l[c]*w[c]; }
  const float inv = 1.f / lsum;

  float o[8] = {};
  #pragma unroll
  for (int c=0;c<NSPLIT;++c) {
    half8 x = *(const half8*)&Opart[((size_t)((c*128 + bh)*LQ + qr))*HD + d0];
    #pragma unroll
    for (int i=0;i<8;++i) o[i] += (float)x[i]*w[c];
  }
  half8 y;
  #pragma unroll
  for (int i=0;i<8;++i) y[i] = (_Float16)(o[i]*inv);
  *(half8*)(aout + ((size_t)(b*LQ + qr))*DM + h*HD + d0) = y;
}

extern "C" void kernel_launch(void* const* d_in, const int* in_sizes, int n_in,
                              void* d_out, int out_size, void* d_ws, size_t ws_size,
                              hipStream_t stream)
{
  const float* qin = (const float*)d_in[0];
  const float* vis = (const float*)d_in[1];
  const float* pk  = (const float*)d_in[2];
  const float* pv  = (const float*)d_in[3];
  const int*   pvl = (const int*)d_in[4];
  const float* cur = (const float*)d_in[5];
  const int*   cvm = (const int*)d_in[6];
  const float* Wq = (const float*)d_in[7];  const float* bq = (const float*)d_in[8];
  const float* Wk = (const float*)d_in[9];  const float* bk = (const float*)d_in[10];
  const float* Wv = (const float*)d_in[11]; const float* bv = (const float*)d_in[12];
  const float* Wo = (const float*)d_in[13]; const float* bo = (const float*)d_in[14];

  char* ws = (char*)d_ws;
  _Float16* Wtq  = (_Float16*)(ws + ((size_t) 0<<20));   // 2 MB each
  _Float16* Wtk  = (_Float16*)(ws + ((size_t) 2<<20));
  _Float16* Wtv  = (_Float16*)(ws + ((size_t) 4<<20));
  _Float16* Wto  = (_Float16*)(ws + ((size_t) 6<<20));
  _Float16* qhp  = (_Float16*)(ws + ((size_t) 8<<20));   // [B,H,256,64]  4 MB
  _Float16* kvcp = (_Float16*)(ws + ((size_t)12<<20));   // [B,H,832,64] 13.6 MB
  _Float16* vvcp = (_Float16*)(ws + ((size_t)26<<20));   // [B,H,832,64] 13.6 MB
  _Float16* aoutp= (_Float16*)(ws + ((size_t)40<<20));   // [B*256,1024]  4 MB
  _Float16* Opart= (_Float16*)(ws + ((size_t)45<<20));   // [8,128,256,64] f16 32 MB
  float*    mpart= (float*)   (ws + ((size_t)77<<20));   // [8,128,256] f32 1 MB
  float*    lpart= (float*)   (ws + ((size_t)78<<20));

  wtrans_k<<<dim3(16,16,4), 256, 0, stream>>>(Wq,Wk,Wv,Wo, Wtq,Wtk,Wtv,Wto);

  proj_k<<<dim3(68,16), 256, 0, stream>>>(qin, vis, cur, Wtq, Wtk, Wtv,
                                          bq, bk, bv, qhp, kvcp, vvcp);

  attn_k<<<dim3(128,NSPLIT), 512, 0, stream>>>(qhp, kvcp, vvcp, pk, pv, pvl, cvm,
                                               Opart, mpart, lpart);

  combine_k<<<dim3(1024), 256, 0, stream>>>(Opart, mpart, lpart, aoutp);

  gemmo_k<<<dim3(16,8), 256, 0, stream>>>(aoutp, Wto, bo, (float*)d_out);
}

// Round 7
// 323.847 us; speedup vs baseline: 1.6779x; 1.0850x over previous
//
#include <hip/hip_runtime.h>

using half8 = __attribute__((ext_vector_type(8))) _Float16;
using f32x4 = __attribute__((ext_vector_type(4))) float;

#define MFMA16(a,b,c) __builtin_amdgcn_mfma_f32_16x16x32_f16((a),(b),(c),0,0,0)

constexpr int DM = 1024;
constexpr int NH = 16;
constexpr int HD = 64;
constexpr int LQ = 256, LV = 576, PP = 2048, LC = 256;
constexpr int KVC = LV + LC;            // 832 (vis rows 0..575, cur rows 576..831)
constexpr int NSPLIT = 8;

// async global->LDS, 16B per lane, wave-uniform LDS base (lane i writes base+i*16)
__device__ __forceinline__ void gload16(const _Float16* g, _Float16* l) {
  __builtin_amdgcn_global_load_lds(
      (const __attribute__((address_space(1))) unsigned int*)g,
      (__attribute__((address_space(3))) unsigned int*)l,
      16, 0, 0);
}

// ---------------- fp32 -> fp16 activation convert (qin, vis, cur) ----------------
__global__ __launch_bounds__(256) void conv_k(
    const float* __restrict__ q, const float* __restrict__ v, const float* __restrict__ c,
    _Float16* __restrict__ qo, _Float16* __restrict__ vo, _Float16* __restrict__ co)
{
  const int a = blockIdx.y;
  const float* src = a==0 ? q : a==1 ? v : c;
  _Float16*   dst  = a==0 ? qo : a==1 ? vo : co;
  const int n = (a==1) ? 8*LV*DM : 8*LQ*DM;
  const int i = (blockIdx.x*256 + threadIdx.x) * 8;
  if (i >= n) return;
  f32x4 x0 = *(const f32x4*)(src+i);
  f32x4 x1 = *(const f32x4*)(src+i+4);
  half8 y;
  #pragma unroll
  for (int j=0;j<4;++j){ y[j]=(_Float16)x0[j]; y[4+j]=(_Float16)x1[j]; }
  *(half8*)(dst+i) = y;
}

// ---------------- W -> W^T fp16 (4 matrices) ----------------
__global__ __launch_bounds__(256) void wtrans_k(
    const float* __restrict__ W0, const float* __restrict__ W1,
    const float* __restrict__ W2, const float* __restrict__ W3,
    _Float16* __restrict__ T0, _Float16* __restrict__ T1,
    _Float16* __restrict__ T2, _Float16* __restrict__ T3)
{
  __shared__ float t[64][65];
  const float* W = blockIdx.z==0 ? W0 : blockIdx.z==1 ? W1 : blockIdx.z==2 ? W2 : W3;
  _Float16*   T  = blockIdx.z==0 ? T0 : blockIdx.z==1 ? T1 : blockIdx.z==2 ? T2 : T3;
  const int k0 = blockIdx.x*64, n0 = blockIdx.y*64;
  const int r = threadIdx.x >> 2, c0 = (threadIdx.x & 3)*16;
  const float* src = W + (size_t)(k0+r)*DM + n0 + c0;
  #pragma unroll
  for (int j=0;j<4;++j) {
    f32x4 v = *(const f32x4*)(src + 4*j);
    #pragma unroll
    for (int i=0;i<4;++i) t[r][c0+4*j+i] = v[i];
  }
  __syncthreads();
  half8 o0, o1;
  #pragma unroll
  for (int i=0;i<8;++i) { o0[i] = (_Float16)t[c0+i][r]; o1[i] = (_Float16)t[c0+8+i][r]; }
  _Float16* dst = T + (size_t)(n0+r)*DM + k0 + c0;
  *(half8*)dst = o0;
  *(half8*)(dst+8) = o1;
}

// ---------------- 128x128 NT GEMM body, fp16 A/W, BK=64, global_load_lds + XOR swizzle ----
// LDS layout: [128][64] fp16; element (row, c8) holds global col-block (c8 ^ (row&7)).
// MODE 0: fp16 head-split out; MODE 1: fp32 flat out.
template<int MODE>
__device__ __forceinline__ void gemm16_body(
    const _Float16* __restrict__ Af, const _Float16* __restrict__ Wt,
    const float* __restrict__ bias, void* __restrict__ outv,
    int L, int off, int LK, int m0, int n0)
{
  __shared__ __align__(16) _Float16 As[128*64];
  __shared__ __align__(16) _Float16 Bs[128*64];
  const int tid = threadIdx.x;
  const int lane = tid & 63, wid = tid >> 6;
  const int l15 = lane & 15, l4 = lane >> 4;
  const int wm = wid >> 1, wn = wid & 1;           // 2x2 waves, 64x64 each
  const int lrow = lane >> 3;                      // 0..7 within 8-row segment
  const int lc8  = lane & 7;                       // 8-fp16 col-block within row

  auto stage = [&](int kt) {
    #pragma unroll
    for (int s8 = 0; s8 < 4; ++s8) {
      const int seg = wid*4 + s8;                  // 16 segments of 8 rows
      const int row = seg*8 + lrow;
      const int c8  = lc8 ^ (row & 7);             // inverse swizzle on global source
      const size_t gc = (size_t)kt*64 + c8*8;
      gload16(Af + (size_t)(m0+row)*DM + gc, &As[seg*512]);
      gload16(Wt + (size_t)(n0+row)*DM + gc, &Bs[seg*512]);
    }
  };

  f32x4 acc[4][4] = {};
  stage(0);

  for (int kt=0; kt<16; ++kt) {
    __syncthreads();                               // drain staging loads
    half8 af[4][2], bf[4][2];
    #pragma unroll
    for (int mf=0; mf<4; ++mf) {
      const int ra = wm*64 + mf*16 + l15;
      const int rb = wn*64 + mf*16 + l15;
      #pragma unroll
      for (int kc=0; kc<2; ++kc) {
        const int g8 = kc*4 + l4;
        af[mf][kc] = *(const half8*)&As[ra*64 + ((g8 ^ (ra&7))<<3)];
        bf[mf][kc] = *(const half8*)&Bs[rb*64 + ((g8 ^ (rb&7))<<3)];
      }
    }
    #pragma unroll
    for (int mf=0;mf<4;++mf)
      #pragma unroll
      for (int nf=0;nf<4;++nf)
        #pragma unroll
        for (int kc=0;kc<2;++kc)
          acc[mf][nf] = MFMA16(af[mf][kc], bf[nf][kc], acc[mf][nf]);
    if (kt < 15) { __syncthreads(); stage(kt+1); } // reads done -> overwrite
  }

  #pragma unroll
  for (int nf=0;nf<4;++nf) {
    const int col = n0 + wn*64 + nf*16 + l15;
    const float bv = bias[col];
    const int hh = col >> 6, dd = col & 63;
    #pragma unroll
    for (int mf=0;mf<4;++mf) {
      const int rbase = m0 + wm*64 + mf*16 + l4*4;
      #pragma unroll
      for (int r=0;r<4;++r) {
        const int t = rbase + r;
        const float v = acc[mf][nf][r] + bv;
        if constexpr (MODE==0) {
          const int bb = t / L, pos = t - bb*L;
          ((_Float16*)outv)[ ((size_t)((bb*NH + hh)*LK + off + pos))*HD + dd ] = (_Float16)v;
        } else {
          ((float*)outv)[ (size_t)t*DM + col ] = v;
        }
      }
    }
  }
}

// ---------------- fused QKV projection ----------------
__global__ __launch_bounds__(256) void proj_k(
    const _Float16* __restrict__ qf, const _Float16* __restrict__ vf, const _Float16* __restrict__ cf,
    const _Float16* __restrict__ Wtq, const _Float16* __restrict__ Wtk, const _Float16* __restrict__ Wtv,
    const float* __restrict__ bq, const float* __restrict__ bk, const float* __restrict__ bv,
    _Float16* __restrict__ qhp, _Float16* __restrict__ kvcp, _Float16* __restrict__ vvcp)
{
  const int bx = blockIdx.x, by = blockIdx.y;
  const _Float16* A; const _Float16* Wt; const float* bias; _Float16* out;
  int m0, n0, L, off, LK;
  if (bx < 16) {
    if (by >= 8) return;
    A = qf; m0 = bx*128; L = LQ; off = 0; LK = LQ;
    Wt = Wtq; bias = bq; out = qhp; n0 = by*128;
  } else {
    if (bx < 52) { A = vf; m0 = (bx-16)*128; L = LV; off = 0; }
    else         { A = cf; m0 = (bx-52)*128; L = LC; off = LV; }
    LK = KVC;
    if (by < 8) { Wt = Wtk; bias = bk; out = kvcp; n0 = by*128; }
    else        { Wt = Wtv; bias = bv; out = vvcp; n0 = (by-8)*128; }
  }
  gemm16_body<0>(A, Wt, bias, out, L, off, LK, m0, n0);
}

// ---------------- output projection ----------------
__global__ __launch_bounds__(256) void gemmo_k(
    const _Float16* __restrict__ A, const _Float16* __restrict__ Wt,
    const float* __restrict__ bias, float* __restrict__ out)
{
  gemm16_body<1>(A, Wt, bias, out, 1, 0, 0, blockIdx.x*128, blockIdx.y*128);
}

// ---------------- flash attention, valid tiles balanced over NSPLIT chunks ----------------
__global__ __launch_bounds__(512) void attn_k(
  const _Float16* __restrict__ qh, const _Float16* __restrict__ kvc,
  const _Float16* __restrict__ vvc, const float* __restrict__ pk,
  const float* __restrict__ pv, const int* __restrict__ pvl,
  const int* __restrict__ cvm, _Float16* __restrict__ Opart,
  float* __restrict__ mpart, float* __restrict__ lpart)
{
  __shared__ __align__(16) _Float16 Ks[64*72];      // [key][d]
  __shared__ __align__(16) _Float16 Vs[64*72];      // [d][key^swz]
  __shared__ float mk[64];
  __shared__ __align__(16) _Float16 Ps[8][16*72];   // per-wave P round-trip (16 rows, 2-step)

  const int bh = blockIdx.x;
  const int ck = blockIdx.y;
  const int b = bh >> 4;
  const int tid = threadIdx.x;
  const int lane = tid & 63, wid = tid >> 6;
  const int l15 = lane & 15, l4 = lane >> 4;

  const int myvl = pvl[b];
  const int vpt = (myvl + 63) >> 6;       // valid past tiles
  const int T = 9 + vpt + 4;              // total valid tiles (13..45)
  const int qn = T >> 3, rr = T & 7;
  const int len = qn + (ck < rr ? 1 : 0);
  const int lo = ck*qn + (ck < rr ? ck : rr);
  const int hi = lo + len;

  half8 aq[2][2];
  {
    const _Float16* qb = qh + ((size_t)bh*LQ + wid*32)*HD;
    #pragma unroll
    for (int rb=0;rb<2;++rb)
      #pragma unroll
      for (int kc=0;kc<2;++kc) {
        half8 x = *(const half8*)(qb + (rb*16+l15)*HD + kc*32 + l4*8);
        #pragma unroll
        for (int j=0;j<8;++j) x[j] = x[j] * (_Float16)0.125f;
        aq[rb][kc] = x;
      }
  }

  f32x4 accO[2][4] = {};
  float mrun[2][4], lrun[2][4];
  #pragma unroll
  for (int rb=0;rb<2;++rb)
    #pragma unroll
    for (int r=0;r<4;++r){ mrun[rb][r] = -3.0e38f; lrun[rb][r] = 0.f; }

  const int skey = tid >> 3;              // 0..63
  const int sd   = (tid & 7) * 8;         // 0..56
  const int vswz = (tid & 7) << 3;
  const int skeyv = skey ^ vswz;

  half8 kreg, vreg;
  f32x4 k0r, k1r, v0r, v1r;
  float mreg = 0.f;
  int ptype = 0;

  auto prefetch = [&](int t) {
    int s;
    if (t < 9)            { ptype = 0; s = t*64; }
    else if (t < 9 + vpt) { ptype = 1; s = (t-9)*64; }
    else                  { ptype = 2; s = LV + (t-9-vpt)*64; }
    if (ptype != 1) {
      const _Float16* kp = kvc + ((size_t)bh*KVC + s)*HD;
      const _Float16* vp = vvc + ((size_t)bh*KVC + s)*HD;
      kreg = *(const half8*)(kp + skey*HD + sd);
      vreg = *(const half8*)(vp + skey*HD + sd);
      if (tid < 64) mreg = (ptype==2) ? (cvm[b*LC + (s - LV) + tid] ? 0.f : -1e30f) : 0.f;
    } else {
      const float* kp = pk + ((size_t)bh*PP + s)*HD;
      const float* vp = pv + ((size_t)bh*PP + s)*HD;
      k0r = *(const f32x4*)(kp + skey*HD + sd);
      k1r = *(const f32x4*)(kp + skey*HD + sd + 4);
      v0r = *(const f32x4*)(vp + skey*HD + sd);
      v1r = *(const f32x4*)(vp + skey*HD + sd + 4);
      if (tid < 64) mreg = (s + tid < myvl) ? 0.f : -1e30f;
    }
  };

  prefetch(lo);

  for (int t=lo; t<hi; ++t) {
    __syncthreads();
    if (ptype != 1) {
      *(half8*)&Ks[skey*72 + sd] = kreg;
      #pragma unroll
      for (int j=0;j<8;++j) Vs[(sd+j)*72 + skeyv] = vreg[j];
    } else {
      half8 kx;
      #pragma unroll
      for (int i=0;i<4;++i){ kx[i] = (_Float16)k0r[i]; kx[4+i] = (_Float16)k1r[i]; }
      *(half8*)&Ks[skey*72 + sd] = kx;
      #pragma unroll
      for (int j=0;j<4;++j) Vs[(sd+j)*72 + skeyv]   = (_Float16)v0r[j];
      #pragma unroll
      for (int j=0;j<4;++j) Vs[(sd+4+j)*72 + skeyv] = (_Float16)v1r[j];
    }
    if (tid < 64) mk[tid] = mreg;
    __syncthreads();
    if (t+1 < hi) prefetch(t+1);

    half8 bk_[4][2];
    #pragma unroll
    for (int nf=0;nf<4;++nf)
      #pragma unroll
      for (int kc=0;kc<2;++kc)
        bk_[nf][kc] = *(const half8*)&Ks[(nf*16+l15)*72 + kc*32 + l4*8];
    f32x4 sf[2][4] = {};
    #pragma unroll
    for (int rb=0;rb<2;++rb)
      #pragma unroll
      for (int nf=0;nf<4;++nf)
        #pragma unroll
        for (int kc=0;kc<2;++kc)
          sf[rb][nf] = MFMA16(aq[rb][kc], bk_[nf][kc], sf[rb][nf]);

    float mc[4];
    #pragma unroll
    for (int nf=0;nf<4;++nf) mc[nf] = mk[nf*16 + l15];
    #pragma unroll
    for (int rb=0;rb<2;++rb)
      #pragma unroll
      for (int nf=0;nf<4;++nf)
        #pragma unroll
        for (int r=0;r<4;++r)
          sf[rb][nf][r] += mc[nf];

    #pragma unroll
    for (int rb=0;rb<2;++rb)
      #pragma unroll
      for (int r=0;r<4;++r) {
        float mx = fmaxf(fmaxf(sf[rb][0][r],sf[rb][1][r]), fmaxf(sf[rb][2][r],sf[rb][3][r]));
        mx = fmaxf(mx, __shfl_xor(mx,1));
        mx = fmaxf(mx, __shfl_xor(mx,2));
        mx = fmaxf(mx, __shfl_xor(mx,4));
        mx = fmaxf(mx, __shfl_xor(mx,8));
        const float mn = fmaxf(mrun[rb][r], mx);
        const float al = __expf(mrun[rb][r] - mn);
        float rs = 0.f;
        #pragma unroll
        for (int nf=0;nf<4;++nf){ float p = __expf(sf[rb][nf][r]-mn); sf[rb][nf][r]=p; rs+=p; }
        rs += __shfl_xor(rs,1);
        rs += __shfl_xor(rs,2);
        rs += __shfl_xor(rs,4);
        rs += __shfl_xor(rs,8);
        lrun[rb][r] = lrun[rb][r]*al + rs;
        mrun[rb][r] = mn;
        #pragma unroll
        for (int df=0;df<4;++df) accO[rb][df][r] *= al;
      }

    half8 bvv[4][2];
    #pragma unroll
    for (int df=0;df<4;++df) {
      const int rot = (df*2 + (l15>>3)) & 7;
      #pragma unroll
      for (int kc=0;kc<2;++kc)
        bvv[df][kc] = *(const half8*)&Vs[(df*16+l15)*72 + ((((kc<<2)|l4) ^ rot) << 3)];
    }

    _Float16* pw = &Ps[wid][0];
    #pragma unroll
    for (int rb=0;rb<2;++rb) {
      #pragma unroll
      for (int nf=0;nf<4;++nf)
        #pragma unroll
        for (int r=0;r<4;++r)
          pw[(l4*4 + r)*72 + nf*16 + l15] = (_Float16)sf[rb][nf][r];

      half8 ap[2];
      #pragma unroll
      for (int kc=0;kc<2;++kc)
        ap[kc] = *(const half8*)&pw[l15*72 + kc*32 + l4*8];

      #pragma unroll
      for (int df=0;df<4;++df)
        #pragma unroll
        for (int kc=0;kc<2;++kc)
          accO[rb][df] = MFMA16(ap[kc], bvv[df][kc], accO[rb][df]);
    }
  }

  const int base = (ck*128 + bh) * LQ;
  #pragma unroll
  for (int rb=0;rb<2;++rb)
    #pragma unroll
    for (int r=0;r<4;++r) {
      const int row = wid*32 + rb*16 + l4*4 + r;
      #pragma unroll
      for (int df=0;df<4;++df)
        Opart[((size_t)(base + row))*HD + df*16 + l15] = (_Float16)accO[rb][df][r];
      if (l15 == 0) {
        mpart[base + row] = mrun[rb][r];
        lpart[base + row] = lrun[rb][r];
      }
    }
}

// ---------------- combine NSPLIT partials -> merged-head fp16 [B*Lq, 1024] ----------------
__global__ __launch_bounds__(256) void combine_k(
    const _Float16* __restrict__ Opart, const float* __restrict__ mpart,
    const float* __restrict__ lpart, _Float16* __restrict__ aout)
{
  const int t = blockIdx.x*256 + threadIdx.x;     // 262144 threads
  const int rg = t >> 3;
  const int d0 = (t & 7) * 8;
  const int bh = rg >> 8, qr = rg & 255;
  const int b = bh >> 4, h = bh & 15;

  float m[NSPLIT], l[NSPLIT];
  float mstar = -3.0e38f;
  #pragma unroll
  for (int c=0;c<NSPLIT;++c) {
    m[c] = mpart[(c*128 + bh)*LQ + qr];
    l[c] = lpart[(c*128 + bh)*LQ + qr];
    mstar = fmaxf(mstar, m[c]);
  }
  float lsum = 0.f, w[NSPLIT];
  #pragma unroll
  for (int c=0;c<NSPLIT;++c) { w[c] = __expf(m[c]-mstar); lsum += l[c]*w[c]; }
  const float inv = 1.f / lsum;

  float o[8] = {};
  #pragma unroll
  for (int c=0;c<NSPLIT;++c) {
    half8 x = *(const half8*)&Opart[((size_t)((c*128 + bh)*LQ + qr))*HD + d0];
    #pragma unroll
    for (int i=0;i<8;++i) o[i] += (float)x[i]*w[c];
  }
  half8 y;
  #pragma unroll
  for (int i=0;i<8;++i) y[i] = (_Float16)(o[i]*inv);
  *(half8*)(aout + ((size_t)(b*LQ + qr))*DM + h*HD + d0) = y;
}

extern "C" void kernel_launch(void* const* d_in, const int* in_sizes, int n_in,
                              void* d_out, int out_size, void* d_ws, size_t ws_size,
                              hipStream_t stream)
{
  const float* qin = (const float*)d_in[0];
  const float* vis = (const float*)d_in[1];
  const float* pk  = (const float*)d_in[2];
  const float* pv  = (const float*)d_in[3];
  const int*   pvl = (const int*)d_in[4];
  const float* cur = (const float*)d_in[5];
  const int*   cvm = (const int*)d_in[6];
  const float* Wq = (const float*)d_in[7];  const float* bq = (const float*)d_in[8];
  const float* Wk = (const float*)d_in[9];  const float* bk = (const float*)d_in[10];
  const float* Wv = (const float*)d_in[11]; const float* bv = (const float*)d_in[12];
  const float* Wo = (const float*)d_in[13]; const float* bo = (const float*)d_in[14];

  char* ws = (char*)d_ws;
  _Float16* Wtq  = (_Float16*)(ws + ((size_t) 0<<20));   // 2 MB each
  _Float16* Wtk  = (_Float16*)(ws + ((size_t) 2<<20));
  _Float16* Wtv  = (_Float16*)(ws + ((size_t) 4<<20));
  _Float16* Wto  = (_Float16*)(ws + ((size_t) 6<<20));
  _Float16* qhp  = (_Float16*)(ws + ((size_t) 8<<20));   // [B,H,256,64]  4 MB
  _Float16* kvcp = (_Float16*)(ws + ((size_t)12<<20));   // [B,H,832,64] 13.6 MB
  _Float16* vvcp = (_Float16*)(ws + ((size_t)26<<20));   // [B,H,832,64] 13.6 MB
  _Float16* aoutp= (_Float16*)(ws + ((size_t)40<<20));   // [B*256,1024]  4 MB
  _Float16* Opart= (_Float16*)(ws + ((size_t)45<<20));   // [8,128,256,64] f16 32 MB (attn phase)
  float*    mpart= (float*)   (ws + ((size_t)77<<20));
  float*    lpart= (float*)   (ws + ((size_t)78<<20));
  // fp16 activations overlay the Opart region (dead before attn_k writes it)
  _Float16* qf16 = (_Float16*)(ws + ((size_t)45<<20));   // 4 MB
  _Float16* vf16 = (_Float16*)(ws + ((size_t)50<<20));   // 9.4 MB
  _Float16* cf16 = (_Float16*)(ws + ((size_t)60<<20));   // 4 MB

  conv_k<<<dim3(2304,3), 256, 0, stream>>>(qin, vis, cur, qf16, vf16, cf16);

  wtrans_k<<<dim3(16,16,4), 256, 0, stream>>>(Wq,Wk,Wv,Wo, Wtq,Wtk,Wtv,Wto);

  proj_k<<<dim3(68,16), 256, 0, stream>>>(qf16, vf16, cf16, Wtq, Wtk, Wtv,
                                          bq, bk, bv, qhp, kvcp, vvcp);

  attn_k<<<dim3(128,NSPLIT), 512, 0, stream>>>(qhp, kvcp, vvcp, pk, pv, pvl, cvm,
                                               Opart, mpart, lpart);

  combine_k<<<dim3(1024), 256, 0, stream>>>(Opart, mpart, lpart, aoutp);

  gemmo_k<<<dim3(16,8), 256, 0, stream>>>(aoutp, Wto, bo, (float*)d_out);
}

// Round 8
// 300.418 us; speedup vs baseline: 1.8087x; 1.0780x over previous
//
#include <hip/hip_runtime.h>

using half8 = __attribute__((ext_vector_type(8))) _Float16;
using half4 = __attribute__((ext_vector_type(4))) _Float16;
using f32x4 = __attribute__((ext_vector_type(4))) float;

#define MFMA16(a,b,c) __builtin_amdgcn_mfma_f32_16x16x32_f16((a),(b),(c),0,0,0)

constexpr int DM = 1024;
constexpr int NH = 16;
constexpr int HD = 64;
constexpr int LQ = 256, LV = 576, PP = 2048, LC = 256;
constexpr int KVC = LV + LC;            // 832 (vis rows 0..575, cur rows 576..831)
constexpr int NSPLIT = 8;

// async global->LDS, 16B per lane, wave-uniform LDS base (lane i writes base+i*16)
__device__ __forceinline__ void gload16(const _Float16* g, _Float16* l) {
  __builtin_amdgcn_global_load_lds(
      (const __attribute__((address_space(1))) unsigned int*)g,
      (__attribute__((address_space(3))) unsigned int*)l,
      16, 0, 0);
}

// ---------------- fp32 -> fp16 activation convert (qin, vis, cur) ----------------
__global__ __launch_bounds__(256) void conv_k(
    const float* __restrict__ q, const float* __restrict__ v, const float* __restrict__ c,
    _Float16* __restrict__ qo, _Float16* __restrict__ vo, _Float16* __restrict__ co)
{
  const int a = blockIdx.y;
  const float* src = a==0 ? q : a==1 ? v : c;
  _Float16*   dst  = a==0 ? qo : a==1 ? vo : co;
  const int n = (a==1) ? 8*LV*DM : 8*LQ*DM;
  const int i = (blockIdx.x*256 + threadIdx.x) * 8;
  if (i >= n) return;
  f32x4 x0 = *(const f32x4*)(src+i);
  f32x4 x1 = *(const f32x4*)(src+i+4);
  half8 y;
  #pragma unroll
  for (int j=0;j<4;++j){ y[j]=(_Float16)x0[j]; y[4+j]=(_Float16)x1[j]; }
  *(half8*)(dst+i) = y;
}

// ---------------- W -> W^T fp16 (4 matrices) ----------------
__global__ __launch_bounds__(256) void wtrans_k(
    const float* __restrict__ W0, const float* __restrict__ W1,
    const float* __restrict__ W2, const float* __restrict__ W3,
    _Float16* __restrict__ T0, _Float16* __restrict__ T1,
    _Float16* __restrict__ T2, _Float16* __restrict__ T3)
{
  __shared__ float t[64][65];
  const float* W = blockIdx.z==0 ? W0 : blockIdx.z==1 ? W1 : blockIdx.z==2 ? W2 : W3;
  _Float16*   T  = blockIdx.z==0 ? T0 : blockIdx.z==1 ? T1 : blockIdx.z==2 ? T2 : T3;
  const int k0 = blockIdx.x*64, n0 = blockIdx.y*64;
  const int r = threadIdx.x >> 2, c0 = (threadIdx.x & 3)*16;
  const float* src = W + (size_t)(k0+r)*DM + n0 + c0;
  #pragma unroll
  for (int j=0;j<4;++j) {
    f32x4 v = *(const f32x4*)(src + 4*j);
    #pragma unroll
    for (int i=0;i<4;++i) t[r][c0+4*j+i] = v[i];
  }
  __syncthreads();
  half8 o0, o1;
  #pragma unroll
  for (int i=0;i<8;++i) { o0[i] = (_Float16)t[c0+i][r]; o1[i] = (_Float16)t[c0+8+i][r]; }
  _Float16* dst = T + (size_t)(n0+r)*DM + k0 + c0;
  *(half8*)dst = o0;
  *(half8*)(dst+8) = o1;
}

// ---------------- 128x128 NT GEMM body, fp16 A/W, BK=64, global_load_lds + XOR swizzle ----
template<int MODE>
__device__ __forceinline__ void gemm16_body(
    const _Float16* __restrict__ Af, const _Float16* __restrict__ Wt,
    const float* __restrict__ bias, void* __restrict__ outv,
    int L, int off, int LK, int m0, int n0)
{
  __shared__ __align__(16) _Float16 As[128*64];
  __shared__ __align__(16) _Float16 Bs[128*64];
  const int tid = threadIdx.x;
  const int lane = tid & 63, wid = tid >> 6;
  const int l15 = lane & 15, l4 = lane >> 4;
  const int wm = wid >> 1, wn = wid & 1;
  const int lrow = lane >> 3;
  const int lc8  = lane & 7;

  auto stage = [&](int kt) {
    #pragma unroll
    for (int s8 = 0; s8 < 4; ++s8) {
      const int seg = wid*4 + s8;
      const int row = seg*8 + lrow;
      const int c8  = lc8 ^ (row & 7);
      const size_t gc = (size_t)kt*64 + c8*8;
      gload16(Af + (size_t)(m0+row)*DM + gc, &As[seg*512]);
      gload16(Wt + (size_t)(n0+row)*DM + gc, &Bs[seg*512]);
    }
  };

  f32x4 acc[4][4] = {};
  stage(0);

  for (int kt=0; kt<16; ++kt) {
    __syncthreads();
    half8 af[4][2], bf[4][2];
    #pragma unroll
    for (int mf=0; mf<4; ++mf) {
      const int ra = wm*64 + mf*16 + l15;
      const int rb = wn*64 + mf*16 + l15;
      #pragma unroll
      for (int kc=0; kc<2; ++kc) {
        const int g8 = kc*4 + l4;
        af[mf][kc] = *(const half8*)&As[ra*64 + ((g8 ^ (ra&7))<<3)];
        bf[mf][kc] = *(const half8*)&Bs[rb*64 + ((g8 ^ (rb&7))<<3)];
      }
    }
    #pragma unroll
    for (int mf=0;mf<4;++mf)
      #pragma unroll
      for (int nf=0;nf<4;++nf)
        #pragma unroll
        for (int kc=0;kc<2;++kc)
          acc[mf][nf] = MFMA16(af[mf][kc], bf[nf][kc], acc[mf][nf]);
    if (kt < 15) { __syncthreads(); stage(kt+1); }
  }

  #pragma unroll
  for (int nf=0;nf<4;++nf) {
    const int col = n0 + wn*64 + nf*16 + l15;
    const float bv = bias[col];
    const int hh = col >> 6, dd = col & 63;
    #pragma unroll
    for (int mf=0;mf<4;++mf) {
      const int rbase = m0 + wm*64 + mf*16 + l4*4;
      #pragma unroll
      for (int r=0;r<4;++r) {
        const int t = rbase + r;
        const float v = acc[mf][nf][r] + bv;
        if constexpr (MODE==0) {
          const int bb = t / L, pos = t - bb*L;
          ((_Float16*)outv)[ ((size_t)((bb*NH + hh)*LK + off + pos))*HD + dd ] = (_Float16)v;
        } else {
          ((float*)outv)[ (size_t)t*DM + col ] = v;
        }
      }
    }
  }
}

// ---------------- fused QKV projection ----------------
__global__ __launch_bounds__(256) void proj_k(
    const _Float16* __restrict__ qf, const _Float16* __restrict__ vf, const _Float16* __restrict__ cf,
    const _Float16* __restrict__ Wtq, const _Float16* __restrict__ Wtk, const _Float16* __restrict__ Wtv,
    const float* __restrict__ bq, const float* __restrict__ bk, const float* __restrict__ bv,
    _Float16* __restrict__ qhp, _Float16* __restrict__ kvcp, _Float16* __restrict__ vvcp)
{
  const int bx = blockIdx.x, by = blockIdx.y;
  const _Float16* A; const _Float16* Wt; const float* bias; _Float16* out;
  int m0, n0, L, off, LK;
  if (bx < 16) {
    if (by >= 8) return;
    A = qf; m0 = bx*128; L = LQ; off = 0; LK = LQ;
    Wt = Wtq; bias = bq; out = qhp; n0 = by*128;
  } else {
    if (bx < 52) { A = vf; m0 = (bx-16)*128; L = LV; off = 0; }
    else         { A = cf; m0 = (bx-52)*128; L = LC; off = LV; }
    LK = KVC;
    if (by < 8) { Wt = Wtk; bias = bk; out = kvcp; n0 = by*128; }
    else        { Wt = Wtv; bias = bv; out = vvcp; n0 = (by-8)*128; }
  }
  gemm16_body<0>(A, Wt, bias, out, L, off, LK, m0, n0);
}

// ---------------- output projection ----------------
__global__ __launch_bounds__(256) void gemmo_k(
    const _Float16* __restrict__ A, const _Float16* __restrict__ Wt,
    const float* __restrict__ bias, float* __restrict__ out)
{
  gemm16_body<1>(A, Wt, bias, out, 1, 0, 0, blockIdx.x*128, blockIdx.y*128);
}

// ---------------- flash attention: swapped QK^T, lane-local softmax, dbuf LDS ----------------
// grid (128, NSPLIT); block 512 = 8 waves x 32 q-rows. Valid tiles balanced over chunks.
// sf = mfma(K, Q): D[key=nf*16+l4*4+r][q=rb*16+l15] -> softmax reduce is in-lane + 2 shuffles.
__global__ __launch_bounds__(512) void attn_k(
  const _Float16* __restrict__ qh, const _Float16* __restrict__ kvc,
  const _Float16* __restrict__ vvc, const float* __restrict__ pk,
  const float* __restrict__ pv, const int* __restrict__ pvl,
  const int* __restrict__ cvm, _Float16* __restrict__ Opart,
  float* __restrict__ mpart, float* __restrict__ lpart)
{
  __shared__ __align__(16) _Float16 Ks[2][64*72];   // [key][d]
  __shared__ __align__(16) _Float16 Vs[2][64*72];   // [d][key^swz]
  __shared__ float mkb[2][64];
  __shared__ __align__(16) _Float16 Ps[8][16*72];   // per-wave P round-trip [q][key]

  const int bh = blockIdx.x, ck = blockIdx.y, b = bh >> 4;
  const int tid = threadIdx.x;
  const int lane = tid & 63, wid = tid >> 6;
  const int l15 = lane & 15, l4 = lane >> 4;

  const int myvl = pvl[b];
  const int vpt = (myvl + 63) >> 6;       // valid past tiles
  const int T = 9 + vpt + 4;              // total valid tiles (13..45)
  const int qn = T >> 3, rr = T & 7;
  const int len = qn + (ck < rr ? 1 : 0);
  const int lo = ck*qn + (ck < rr ? ck : rr);
  const int hi = lo + len;

  // Q fragments (B-operand: col=q-row), pre-scaled by 1/sqrt(64)
  half8 aq[2][2];
  {
    const _Float16* qb = qh + ((size_t)bh*LQ + wid*32)*HD;
    #pragma unroll
    for (int rb=0;rb<2;++rb)
      #pragma unroll
      for (int kc=0;kc<2;++kc) {
        half8 x = *(const half8*)(qb + (rb*16+l15)*HD + kc*32 + l4*8);
        #pragma unroll
        for (int j=0;j<8;++j) x[j] = x[j] * (_Float16)0.125f;
        aq[rb][kc] = x;
      }
  }

  f32x4 accO[2][4] = {};                  // D[q=l4*4+r][d=df*16+l15] per rb
  float mrun2[2] = {-3.0e38f, -3.0e38f};  // per q=rb*16+l15 (uniform over l4)
  float lrun2[2] = {0.f, 0.f};

  const int skey = tid >> 3;              // 0..63
  const int sd   = (tid & 7) * 8;         // 0..56
  const int vswz = (tid & 7) << 3;
  const int skeyv = skey ^ vswz;

  half8 kreg, vreg;
  f32x4 k0r, k1r, v0r, v1r;
  float mreg = 0.f;
  int ptype = 0;

  auto prefetch = [&](int t) {
    int s;
    if (t < 9)            { ptype = 0; s = t*64; }
    else if (t < 9 + vpt) { ptype = 1; s = (t-9)*64; }
    else                  { ptype = 2; s = LV + (t-9-vpt)*64; }
    if (ptype != 1) {
      const _Float16* kp = kvc + ((size_t)bh*KVC + s)*HD;
      const _Float16* vp = vvc + ((size_t)bh*KVC + s)*HD;
      kreg = *(const half8*)(kp + skey*HD + sd);
      vreg = *(const half8*)(vp + skey*HD + sd);
      if (tid < 64) mreg = (ptype==2) ? (cvm[b*LC + (s - LV) + tid] ? 0.f : -1e30f) : 0.f;
    } else {
      const float* kp = pk + ((size_t)bh*PP + s)*HD;
      const float* vp = pv + ((size_t)bh*PP + s)*HD;
      k0r = *(const f32x4*)(kp + skey*HD + sd);
      k1r = *(const f32x4*)(kp + skey*HD + sd + 4);
      v0r = *(const f32x4*)(vp + skey*HD + sd);
      v1r = *(const f32x4*)(vp + skey*HD + sd + 4);
      if (tid < 64) mreg = (s + tid < myvl) ? 0.f : -1e30f;
    }
  };

  auto writeLDS = [&](int buf) {
    if (ptype != 1) {
      *(half8*)&Ks[buf][skey*72 + sd] = kreg;
      #pragma unroll
      for (int j=0;j<8;++j) Vs[buf][(sd+j)*72 + skeyv] = vreg[j];
    } else {
      half8 kx;
      #pragma unroll
      for (int i=0;i<4;++i){ kx[i] = (_Float16)k0r[i]; kx[4+i] = (_Float16)k1r[i]; }
      *(half8*)&Ks[buf][skey*72 + sd] = kx;
      #pragma unroll
      for (int j=0;j<4;++j) Vs[buf][(sd+j)*72 + skeyv]   = (_Float16)v0r[j];
      #pragma unroll
      for (int j=0;j<4;++j) Vs[buf][(sd+4+j)*72 + skeyv] = (_Float16)v1r[j];
    }
    if (tid < 64) mkb[buf][tid] = mreg;
  };

  prefetch(lo);
  writeLDS(0);

  for (int t=lo; t<hi; ++t) {
    const int cur = (t - lo) & 1;
    if (t+1 < hi) prefetch(t+1);          // loads fly across barrier + compute
    __syncthreads();                      // buf[cur] writes visible to all waves

    // K fragments (A-operand: row=key) + swapped QK^T
    half8 bk_[4][2];
    #pragma unroll
    for (int nf=0;nf<4;++nf)
      #pragma unroll
      for (int kc=0;kc<2;++kc)
        bk_[nf][kc] = *(const half8*)&Ks[cur][(nf*16+l15)*72 + kc*32 + l4*8];
    f32x4 sf[2][4] = {};
    #pragma unroll
    for (int rb=0;rb<2;++rb)
      #pragma unroll
      for (int nf=0;nf<4;++nf)
        #pragma unroll
        for (int kc=0;kc<2;++kc)
          sf[rb][nf] = MFMA16(bk_[nf][kc], aq[rb][kc], sf[rb][nf]);

    // V fragments (swizzle-compensated)
    half8 bvv[4][2];
    #pragma unroll
    for (int df=0;df<4;++df) {
      const int rot = (df*2 + (l15>>3)) & 7;
      #pragma unroll
      for (int kc=0;kc<2;++kc)
        bvv[df][kc] = *(const half8*)&Vs[cur][(df*16+l15)*72 + ((((kc<<2)|l4) ^ rot) << 3)];
    }

    // mask add: key = nf*16 + l4*4 + r
    f32x4 mc[4];
    #pragma unroll
    for (int nf=0;nf<4;++nf) mc[nf] = *(const f32x4*)&mkb[cur][nf*16 + l4*4];
    #pragma unroll
    for (int rb=0;rb<2;++rb)
      #pragma unroll
      for (int nf=0;nf<4;++nf)
        sf[rb][nf] += mc[nf];

    // softmax: q-row = rb*16+l15; 16 keys in-lane, x4 across l4-groups
    #pragma unroll
    for (int rb=0;rb<2;++rb) {
      float mx = sf[rb][0][0];
      #pragma unroll
      for (int nf=0;nf<4;++nf)
        #pragma unroll
        for (int r=0;r<4;++r) mx = fmaxf(mx, sf[rb][nf][r]);
      mx = fmaxf(mx, __shfl_xor(mx, 16));
      mx = fmaxf(mx, __shfl_xor(mx, 32));
      const float mn = fmaxf(mrun2[rb], mx);
      const float al = __expf(mrun2[rb] - mn);
      float rs = 0.f;
      #pragma unroll
      for (int nf=0;nf<4;++nf)
        #pragma unroll
        for (int r=0;r<4;++r) {
          const float p = __expf(sf[rb][nf][r] - mn);
          sf[rb][nf][r] = p;
          rs += p;
        }
      rs += __shfl_xor(rs, 16);
      rs += __shfl_xor(rs, 32);
      lrun2[rb] = lrun2[rb]*al + rs;
      mrun2[rb] = mn;
      #pragma unroll
      for (int r=0;r<4;++r) {
        const float alr = __shfl(al, l4*4 + r);   // al for q-row l4*4+r
        #pragma unroll
        for (int df=0;df<4;++df) accO[rb][df][r] *= alr;
      }
    }

    // P -> LDS (vector b64: keys r=0..3 contiguous) then PV
    _Float16* pw = &Ps[wid][0];
    #pragma unroll
    for (int rb=0;rb<2;++rb) {
      #pragma unroll
      for (int nf=0;nf<4;++nf) {
        half4 h;
        #pragma unroll
        for (int r=0;r<4;++r) h[r] = (_Float16)sf[rb][nf][r];
        *(half4*)&pw[l15*72 + nf*16 + l4*4] = h;
      }
      half8 ap[2];
      #pragma unroll
      for (int kc=0;kc<2;++kc)
        ap[kc] = *(const half8*)&pw[l15*72 + kc*32 + l4*8];
      #pragma unroll
      for (int df=0;df<4;++df)
        #pragma unroll
        for (int kc=0;kc<2;++kc)
          accO[rb][df] = MFMA16(ap[kc], bvv[df][kc], accO[rb][df]);
    }

    if (t+1 < hi) writeLDS(cur ^ 1);      // next tile into the other buffer
  }

  // epilogue: unnormalized fp16 partials + (m,l)
  const int base = (ck*128 + bh) * LQ;
  #pragma unroll
  for (int rb=0;rb<2;++rb) {
    #pragma unroll
    for (int r=0;r<4;++r) {
      const int row = wid*32 + rb*16 + l4*4 + r;
      #pragma unroll
      for (int df=0;df<4;++df)
        Opart[((size_t)(base + row))*HD + df*16 + l15] = (_Float16)accO[rb][df][r];
    }
    if (l4 == 0) {
      mpart[base + wid*32 + rb*16 + l15] = mrun2[rb];
      lpart[base + wid*32 + rb*16 + l15] = lrun2[rb];
    }
  }
}

// ---------------- combine NSPLIT partials -> merged-head fp16 [B*Lq, 1024] ----------------
__global__ __launch_bounds__(256) void combine_k(
    const _Float16* __restrict__ Opart, const float* __restrict__ mpart,
    const float* __restrict__ lpart, _Float16* __restrict__ aout)
{
  const int t = blockIdx.x*256 + threadIdx.x;     // 262144 threads
  const int rg = t >> 3;
  const int d0 = (t & 7) * 8;
  const int bh = rg >> 8, qr = rg & 255;
  const int b = bh >> 4, h = bh & 15;

  float m[NSPLIT], l[NSPLIT];
  float mstar = -3.0e38f;
  #pragma unroll
  for (int c=0;c<NSPLIT;++c) {
    m[c] = mpart[(c*128 + bh)*LQ + qr];
    l[c] = lpart[(c*128 + bh)*LQ + qr];
    mstar = fmaxf(mstar, m[c]);
  }
  float lsum = 0.f, w[NSPLIT];
  #pragma unroll
  for (int c=0;c<NSPLIT;++c) { w[c] = __expf(m[c]-mstar); lsum += l[c]*w[c]; }
  const float inv = 1.f / lsum;

  float o[8] = {};
  #pragma unroll
  for (int c=0;c<NSPLIT;++c) {
    half8 x = *(const half8*)&Opart[((size_t)((c*128 + bh)*LQ + qr))*HD + d0];
    #pragma unroll
    for (int i=0;i<8;++i) o[i] += (float)x[i]*w[c];
  }
  half8 y;
  #pragma unroll
  for (int i=0;i<8;++i) y[i] = (_Float16)(o[i]*inv);
  *(half8*)(aout + ((size_t)(b*LQ + qr))*DM + h*HD + d0) = y;
}

extern "C" void kernel_launch(void* const* d_in, const int* in_sizes, int n_in,
                              void* d_out, int out_size, void* d_ws, size_t ws_size,
                              hipStream_t stream)
{
  const float* qin = (const float*)d_in[0];
  const float* vis = (const float*)d_in[1];
  const float* pk  = (const float*)d_in[2];
  const float* pv  = (const float*)d_in[3];
  const int*   pvl = (const int*)d_in[4];
  const float* cur = (const float*)d_in[5];
  const int*   cvm = (const int*)d_in[6];
  const float* Wq = (const float*)d_in[7];  const float* bq = (const float*)d_in[8];
  const float* Wk = (const float*)d_in[9];  const float* bk = (const float*)d_in[10];
  const float* Wv = (const float*)d_in[11]; const float* bv = (const float*)d_in[12];
  const float* Wo = (const float*)d_in[13]; const float* bo = (const float*)d_in[14];

  char* ws = (char*)d_ws;
  _Float16* Wtq  = (_Float16*)(ws + ((size_t) 0<<20));   // 2 MB each
  _Float16* Wtk  = (_Float16*)(ws + ((size_t) 2<<20));
  _Float16* Wtv  = (_Float16*)(ws + ((size_t) 4<<20));
  _Float16* Wto  = (_Float16*)(ws + ((size_t) 6<<20));
  _Float16* qhp  = (_Float16*)(ws + ((size_t) 8<<20));   // [B,H,256,64]  4 MB
  _Float16* kvcp = (_Float16*)(ws + ((size_t)12<<20));   // [B,H,832,64] 13.6 MB
  _Float16* vvcp = (_Float16*)(ws + ((size_t)26<<20));   // [B,H,832,64] 13.6 MB
  _Float16* aoutp= (_Float16*)(ws + ((size_t)40<<20));   // [B*256,1024]  4 MB
  _Float16* Opart= (_Float16*)(ws + ((size_t)45<<20));   // [8,128,256,64] f16 32 MB (attn phase)
  float*    mpart= (float*)   (ws + ((size_t)77<<20));
  float*    lpart= (float*)   (ws + ((size_t)78<<20));
  // fp16 activations overlay the Opart region (dead before attn_k writes it)
  _Float16* qf16 = (_Float16*)(ws + ((size_t)45<<20));   // 4 MB
  _Float16* vf16 = (_Float16*)(ws + ((size_t)50<<20));   // 9.4 MB
  _Float16* cf16 = (_Float16*)(ws + ((size_t)60<<20));   // 4 MB

  conv_k<<<dim3(2304,3), 256, 0, stream>>>(qin, vis, cur, qf16, vf16, cf16);

  wtrans_k<<<dim3(16,16,4), 256, 0, stream>>>(Wq,Wk,Wv,Wo, Wtq,Wtk,Wtv,Wto);

  proj_k<<<dim3(68,16), 256, 0, stream>>>(qf16, vf16, cf16, Wtq, Wtk, Wtv,
                                          bq, bk, bv, qhp, kvcp, vvcp);

  attn_k<<<dim3(128,NSPLIT), 512, 0, stream>>>(qhp, kvcp, vvcp, pk, pv, pvl, cvm,
                                               Opart, mpart, lpart);

  combine_k<<<dim3(1024), 256, 0, stream>>>(Opart, mpart, lpart, aoutp);

  gemmo_k<<<dim3(16,8), 256, 0, stream>>>(aoutp, Wto, bo, (float*)d_out);
}